// Round 13
// baseline (200.969 us; speedup 1.0000x reference)
//
#include <hip/hip_runtime.h>
#include <hip/hip_bf16.h>
#include <hip/hip_fp16.h>
#include <math.h>

#define HDIM 64
#define NN   100000
#define NE   1600000
#define TEMP 30.0f
#define LNEPS 1e-5f

// bucketing: 64 nodes per bucket; privatized sort over 64 exclusive edge ranges
#define GSH   6
#define GSZ   64
#define NB    1563           // ceil(NN/64) buckets
#define NBLK  64             // privatized hist/scatter blocks (exclusive ranges)
#define EPB   (NE / NBLK)    // 25000 edges per block
#define NCNT  (NB * NBLK)    // 100032 per-(bucket,block) counters
#define SCANB2 98            // ceil(NCNT/1024)
#define FSTR  72             // padded LDS row stride (words): conflict-free b128
#define ZBLK  1563           // mi-zero blocks in front_kernel (16KB each)

typedef __attribute__((ext_vector_type(8))) short bf16x8;
typedef __attribute__((ext_vector_type(4))) float f32x4;
typedef _Float16 __attribute__((ext_vector_type(2))) h2t;

__device__ __forceinline__ short f2bf(float f) {
    __hip_bfloat16 b = __float2bfloat16(f);
    short s; __builtin_memcpy(&s, &b, 2); return s;
}
__device__ __forceinline__ unsigned pk2(float lo, float hi) {
    return (unsigned)(unsigned short)f2bf(lo) | ((unsigned)(unsigned short)f2bf(hi) << 16);
}
__device__ __forceinline__ short f2h(float f) {
    __half h = __float2half(f);
    short s; __builtin_memcpy(&s, &h, 2); return s;
}
__device__ __forceinline__ unsigned pk2h(float lo, float hi) {
    return (unsigned)(unsigned short)f2h(lo) | ((unsigned)(unsigned short)f2h(hi) << 16);
}
// packed fp16 add + relu: v_pk_add_f16 + 3-op sign-mask zeroing
__device__ __forceinline__ unsigned pk_add_relu(unsigned a, unsigned b) {
    h2t x, y;
    __builtin_memcpy(&x, &a, 4); __builtin_memcpy(&y, &b, 4);
    h2t r = x + y;
    unsigned u; __builtin_memcpy(&u, &r, 4);
    const unsigned msk = ((u & 0x80008000u) >> 15) * 0xFFFFu;
    return u & ~msk;
}
__device__ __forceinline__ float sigmoidf_(float z) { return 1.0f / (1.0f + __expf(-z)); }

// ==== Front kernel: hist (64) || pre (512) || optional mi-zero (1563) ====
extern "C" __global__ void __launch_bounds__(256, 2)
front_kernel(const float* __restrict__ h,
             const float* __restrict__ We1, const float* __restrict__ be1,
             unsigned short* __restrict__ Pt, unsigned short* __restrict__ Pb,
             const int* __restrict__ ei, int* __restrict__ cnt3,
             float* __restrict__ mi_zero)
{
    __shared__ float fx[4][1024];    // 16 KB: pre transpose buffers / hist bins
    const int b = blockIdx.x;

    if (b >= NBLK + 512) {
        // ---- mi-zero role (non-aliased path only) ----
        const int zb = b - NBLK - 512;
        const size_t base = (size_t)zb * 4096;
        float4* dst = (float4*)(mi_zero + base);
        const size_t total = (size_t)NN * 64;
        #pragma unroll
        for (int i = threadIdx.x; i < 1024; i += 256)
            if (base + (size_t)i * 4 < total)
                dst[i] = (float4){0.f, 0.f, 0.f, 0.f};
        return;
    }

    if (b < NBLK) {
        // ---- hist role: zero global atomics ----
        int* hbin = (int*)&fx[0][0];           // 1563 ints (6.25 KB)
        const int tid = threadIdx.x;
        for (int k = tid; k < NB; k += 256) hbin[k] = 0;
        __syncthreads();
        const int i0 = b * EPB;
        for (int i = i0 + tid; i < i0 + EPB; i += 256)
            atomicAdd(&hbin[ei[NE + i] >> GSH], 1);
        __syncthreads();
        for (int k = tid; k < NB; k += 256)
            cnt3[k * NBLK + b] = hbin[k];      // exclusive slot: plain store
        return;
    }

    // ---- pre role ----
    const int pb   = b - NBLK;
    const int tid  = threadIdx.x;
    const int wib  = tid >> 6;
    const int lane = tid & 63;
    const int e = lane & 15, g = lane >> 4;
    float* fb = &fx[wib][0];
    const int se = ((e & 1) << 4) | ((e >> 1) & 3);

    bf16x8 At[4][2], Ab[4][2];
    f32x4 b1r[4];
    #pragma unroll
    for (int t = 0; t < 4; ++t) {
        #pragma unroll
        for (int ks = 0; ks < 2; ++ks) {
            bf16x8 a, bb;
            #pragma unroll
            for (int j = 0; j < 8; ++j) {
                a[j]  = f2bf(We1[(32 * ks + 8 * g + j) * 64 + 16 * t + e]);
                bb[j] = f2bf(We1[(64 + 32 * ks + 8 * g + j) * 64 + 16 * t + e]);
            }
            At[t][ks] = a; Ab[t][ks] = bb;
        }
        #pragma unroll
        for (int r = 0; r < 4; ++r) b1r[t][r] = be1[16 * t + 4 * g + r];
    }

    const int gwid = pb * 4 + wib;
    const int nw   = 512 * 4;

    for (int tile = gwid; tile < NN / 16; tile += nw) {
        const int node = tile * 16 + e;

        bf16x8 B[2];
        #pragma unroll
        for (int ks = 0; ks < 2; ++ks) {
            const float4* p = (const float4*)(h + (size_t)node * 64 + ks * 32 + 8 * g);
            const float4 f0 = p[0], f1 = p[1];
            bf16x8 bb;
            bb[0] = f2bf(f0.x); bb[1] = f2bf(f0.y); bb[2] = f2bf(f0.z); bb[3] = f2bf(f0.w);
            bb[4] = f2bf(f1.x); bb[5] = f2bf(f1.y); bb[6] = f2bf(f1.z); bb[7] = f2bf(f1.w);
            B[ks] = bb;
        }

        f32x4 aT[4], aB[4];
        #pragma unroll
        for (int t = 0; t < 4; ++t) {
            aT[t] = b1r[t];
            aB[t] = (f32x4){0.f, 0.f, 0.f, 0.f};
            #pragma unroll
            for (int ks = 0; ks < 2; ++ks) {
                aT[t] = __builtin_amdgcn_mfma_f32_16x16x32_bf16(At[t][ks], B[ks], aT[t], 0, 0, 0);
                aB[t] = __builtin_amdgcn_mfma_f32_16x16x32_bf16(Ab[t][ks], B[ks], aB[t], 0, 0, 0);
            }
        }

        #pragma unroll
        for (int t = 0; t < 4; ++t)
            #pragma unroll
            for (int r = 0; r < 4; ++r)
                fb[e * 64 + ((16 * t + 4 * g + r) ^ se)] = aT[t][r];
        #pragma unroll
        for (int q = 0; q < 2; ++q) {
            const int row = q * 8 + (lane >> 3);
            const int sr  = ((row & 1) << 4) | ((row >> 1) & 3);
            const int c0  = (lane & 7) * 8;
            uint4 o;
            o.x = pk2h(fb[row * 64 + ((c0 + 0) ^ sr)], fb[row * 64 + ((c0 + 1) ^ sr)]);
            o.y = pk2h(fb[row * 64 + ((c0 + 2) ^ sr)], fb[row * 64 + ((c0 + 3) ^ sr)]);
            o.z = pk2h(fb[row * 64 + ((c0 + 4) ^ sr)], fb[row * 64 + ((c0 + 5) ^ sr)]);
            o.w = pk2h(fb[row * 64 + ((c0 + 6) ^ sr)], fb[row * 64 + ((c0 + 7) ^ sr)]);
            *(uint4*)((char*)Pt + (size_t)tile * 2048 + q * 1024 + lane * 16) = o;
        }

        #pragma unroll
        for (int t = 0; t < 4; ++t)
            #pragma unroll
            for (int r = 0; r < 4; ++r)
                fb[e * 64 + ((16 * t + 4 * g + r) ^ se)] = aB[t][r];
        #pragma unroll
        for (int q = 0; q < 2; ++q) {
            const int row = q * 8 + (lane >> 3);
            const int sr  = ((row & 1) << 4) | ((row >> 1) & 3);
            const int c0  = (lane & 7) * 8;
            uint4 o;
            o.x = pk2h(fb[row * 64 + ((c0 + 0) ^ sr)], fb[row * 64 + ((c0 + 1) ^ sr)]);
            o.y = pk2h(fb[row * 64 + ((c0 + 2) ^ sr)], fb[row * 64 + ((c0 + 3) ^ sr)]);
            o.z = pk2h(fb[row * 64 + ((c0 + 4) ^ sr)], fb[row * 64 + ((c0 + 5) ^ sr)]);
            o.w = pk2h(fb[row * 64 + ((c0 + 6) ^ sr)], fb[row * 64 + ((c0 + 7) ^ sr)]);
            *(uint4*)((char*)Pb + (size_t)tile * 2048 + q * 1024 + lane * 16) = o;
        }
    }
}

// ============ Hierarchical exclusive scan of cnt3[NCNT] -> off3 ============
extern "C" __global__ void __launch_bounds__(1024)
scanA_kernel(const int* __restrict__ cnt3, int* __restrict__ off3, int* __restrict__ bsum)
{
    __shared__ int sh[1024];
    const int t = threadIdx.x;
    const int i = blockIdx.x * 1024 + t;
    const int v = (i < NCNT) ? cnt3[i] : 0;
    sh[t] = v;
    __syncthreads();
    for (int off = 1; off < 1024; off <<= 1) {
        const int u = (t >= off) ? sh[t - off] : 0;
        __syncthreads();
        sh[t] += u;
        __syncthreads();
    }
    if (i < NCNT) off3[i] = sh[t] - v;
    if (t == 1023) bsum[blockIdx.x] = sh[1023];
}

// scanC (merged with old scanB): each block redundantly reduces bsum[0..blk)
extern "C" __global__ void __launch_bounds__(1024)
scanC_kernel(int* __restrict__ off3, const int* __restrict__ bsum)
{
    __shared__ int boff;
    const int t = threadIdx.x;
    if (t < 64) {
        int v = 0;
        for (int j = t; j < blockIdx.x; j += 64) v += bsum[j];
        #pragma unroll
        for (int off = 1; off < 64; off <<= 1) v += __shfl_xor(v, off);
        if (t == 0) boff = v;
    }
    __syncthreads();
    const int i = blockIdx.x * 1024 + t;
    if (i < NCNT) off3[i] += boff;
}

// ============ Privatized scatter: LDS cursors, zero global atomics ============
extern "C" __global__ void __launch_bounds__(1024)
scatter3_kernel(const int* __restrict__ ei, const int* __restrict__ off3,
                unsigned* __restrict__ sedge)
{
    __shared__ int cur[NB];
    const int b   = blockIdx.x;                  // grid must be NBLK
    const int tid = threadIdx.x;
    for (int k = tid; k < NB; k += 1024) cur[k] = off3[k * NBLK + b];
    __syncthreads();
    const int i0 = b * EPB;
    for (int i = i0 + tid; i < i0 + EPB; i += 1024) {
        const int s = ei[i];
        const int d = ei[NE + i];
        const int pos = atomicAdd(&cur[d >> GSH], 1);   // LDS atomic
        sedge[pos] = (unsigned)s | ((unsigned)(d & (GSZ - 1)) << 17);
    }
}

// ============ Per-bucket exact refinement sort ============
extern "C" __global__ void __launch_bounds__(256)
sort2_kernel(const unsigned* __restrict__ sedge, const int* __restrict__ off3,
             int2* __restrict__ spair)
{
    __shared__ int hist[GSZ], base[GSZ], curs[GSZ];
    const int tid = threadIdx.x;
    const int b   = blockIdx.x;
    const int r0  = off3[b * NBLK];
    const int r1  = (b == NB - 1) ? NE : off3[(b + 1) * NBLK];

    if (tid < GSZ) hist[tid] = 0;
    __syncthreads();
    for (int i = r0 + tid; i < r1; i += 256)
        atomicAdd(&hist[(sedge[i] >> 17) & (GSZ - 1)], 1);
    __syncthreads();
    if (tid == 0) {
        int run = 0;
        for (int j = 0; j < GSZ; ++j) { base[j] = run; run += hist[j]; }
    }
    __syncthreads();
    if (tid < GSZ) curs[tid] = base[tid];
    __syncthreads();
    for (int i = r0 + tid; i < r1; i += 256) {
        const unsigned pk = sedge[i];
        const int dl = (pk >> 17) & (GSZ - 1);
        const int pos = r0 + atomicAdd(&curs[dl], 1);
        spair[pos] = make_int2((int)(pk & 0x1FFFFu), (b << GSH) | dl);
    }
}

// ============ Edge kernel (sorted): pipelined gathers + run accumulation ====
// Software pipeline: spair prefetched 2 tiles ahead; Pt/Pb gathers issued one
// tile ahead so HBM/L2 latency hides under the current tile's compute+flush.
extern "C" __global__ void __launch_bounds__(256, 2)
edge_kernel_sorted(const unsigned short* __restrict__ Pt, const unsigned short* __restrict__ Pb,
                   const float* __restrict__ x, const int2* __restrict__ spair,
                   const float* __restrict__ We2, const float* __restrict__ be2,
                   const float* __restrict__ Winf, const float* __restrict__ binf,
                   float* __restrict__ mi)
{
    __shared__ float fx[4][16 * FSTR];   // 18 KB
    const int tid  = threadIdx.x;
    const int wib  = tid >> 6;
    const int lane = tid & 63;
    const int e = lane & 15, g = lane >> 4;
    float* fb = &fx[wib][0];

    bf16x8 A2[4][2];                        // fp16 fragments
    f32x4 b2r[4], wir[4];
    #pragma unroll
    for (int t = 0; t < 4; ++t) {
        #pragma unroll
        for (int ks = 0; ks < 2; ++ks) {
            bf16x8 a;
            #pragma unroll
            for (int j = 0; j < 8; ++j)
                a[j] = f2h(We2[(32 * ks + 8 * g + j) * 64 + 16 * t + e]);
            A2[t][ks] = a;
        }
        #pragma unroll
        for (int r = 0; r < 4; ++r) {
            b2r[t][r] = be2[16 * t + 4 * g + r];
            wir[t][r] = Winf[16 * t + 4 * g + r];
        }
    }
    const float binf0 = binf[0];

    const int NT     = NE / 16;
    const int nwaves = gridDim.x * 4;
    const int gwid   = blockIdx.x * 4 + wib;
    const int chunk  = (NT + nwaves - 1) / nwaves;
    const int t0 = gwid * chunk;
    const int t1 = (t0 + chunk < NT) ? t0 + chunk : NT;

    float racc  = 0.f;   // running row accumulator, channel = lane
    int   rrow  = -1;    // wave-uniform current node id

    int2 sdA, sdB;
    uint4 g0, g1, g2, g3;   // Pt lo/hi, Pb lo/hi for current tile
    if (t0 < t1) {
        sdA = spair[t0 * 16 + e];
        g0 = *(const uint4*)(Pt + (size_t)sdA.y * 64 + 8 * g);
        g1 = *(const uint4*)(Pt + (size_t)sdA.y * 64 + 32 + 8 * g);
        g2 = *(const uint4*)(Pb + (size_t)sdA.x * 64 + 8 * g);
        g3 = *(const uint4*)(Pb + (size_t)sdA.x * 64 + 32 + 8 * g);
        sdB = (t0 + 1 < t1) ? spair[(t0 + 1) * 16 + e] : sdA;
    }

    for (int tile = t0; tile < t1; ++tile) {
        // prefetch spair two tiles ahead; issue next tile's gathers now
        const int2 sdC = (tile + 2 < t1) ? spair[(tile + 2) * 16 + e] : sdB;
        const uint4 n0 = *(const uint4*)(Pt + (size_t)sdB.y * 64 + 8 * g);
        const uint4 n1 = *(const uint4*)(Pt + (size_t)sdB.y * 64 + 32 + 8 * g);
        const uint4 n2 = *(const uint4*)(Pb + (size_t)sdB.x * 64 + 8 * g);
        const uint4 n3 = *(const uint4*)(Pb + (size_t)sdB.x * 64 + 32 + 8 * g);

        const int sN = sdA.x;
        const int dN = sdA.y;

        const float dx = x[dN * 3 + 0] - x[sN * 3 + 0];
        const float dy = x[dN * 3 + 1] - x[sN * 3 + 1];
        const float dz = x[dN * 3 + 2] - x[sN * 3 + 2];
        const float dsq = dx * dx + dy * dy + dz * dz;
        const float edis = sigmoidf_(TEMP / (sqrtf(dsq) + 1e-8f));

        // B2 frags: relu(Pt[dst] + Pb[src]) in packed fp16
        bf16x8 B2[2];
        {
            union { uint4 u; bf16x8 b; } c0, c1;
            c0.u.x = pk_add_relu(g0.x, g2.x);
            c0.u.y = pk_add_relu(g0.y, g2.y);
            c0.u.z = pk_add_relu(g0.z, g2.z);
            c0.u.w = pk_add_relu(g0.w, g2.w);
            c1.u.x = pk_add_relu(g1.x, g3.x);
            c1.u.y = pk_add_relu(g1.y, g3.y);
            c1.u.z = pk_add_relu(g1.z, g3.z);
            c1.u.w = pk_add_relu(g1.w, g3.w);
            B2[0] = c0.b; B2[1] = c1.b;
        }

        f32x4 acc2[4];
        #pragma unroll
        for (int t = 0; t < 4; ++t) {
            acc2[t] = b2r[t];
            #pragma unroll
            for (int ks = 0; ks < 2; ++ks)
                acc2[t] = __builtin_amdgcn_mfma_f32_16x16x32_f16(A2[t][ks], B2[ks], acc2[t], 0, 0, 0);
        }

        float m[4][4];
        float p = 0.f;
        #pragma unroll
        for (int t = 0; t < 4; ++t)
            #pragma unroll
            for (int r = 0; r < 4; ++r) {
                m[t][r] = fmaxf(acc2[t][r], 0.f);
                p = fmaf(m[t][r], wir[t][r], p);
            }
        p += __shfl_xor(p, 16);
        p += __shfl_xor(p, 32);
        const float w = sigmoidf_((p + binf0) * edis);

        // transpose via 4x ds_write_b128, natural channel order, stride-72 rows
        #pragma unroll
        for (int t = 0; t < 4; ++t) {
            float4 v;
            v.x = m[t][0] * w; v.y = m[t][1] * w;
            v.z = m[t][2] * w; v.w = m[t][3] * w;
            *(float4*)&fb[e * FSTR + 16 * t + 4 * g] = v;
        }

        #pragma unroll
        for (int i = 0; i < 16; ++i) {
            const int row = __builtin_amdgcn_readlane(sdA.y, i);
            const float v = fb[i * FSTR + lane];
            if (row != rrow) {
                if (rrow >= 0) atomicAdd(mi + (size_t)rrow * 64 + lane, racc);
                rrow = row; racc = v;
            } else {
                racc += v;
            }
        }

        sdA = sdB; sdB = sdC;
        g0 = n0; g1 = n1; g2 = n2; g3 = n3;
    }
    if (rrow >= 0) atomicAdd(mi + (size_t)rrow * 64 + lane, racc);
}

// ============ Edge kernel (unsorted fallback, small-ws path) ============
extern "C" __global__ void __launch_bounds__(256, 2)
edge_kernel_unsorted(const unsigned short* __restrict__ Pt, const unsigned short* __restrict__ Pb,
                     const float* __restrict__ x, const int* __restrict__ ei,
                     const float* __restrict__ We2, const float* __restrict__ be2,
                     const float* __restrict__ Winf, const float* __restrict__ binf,
                     float* __restrict__ mi)
{
    __shared__ float fx[4][16 * FSTR];
    const int tid  = threadIdx.x;
    const int wib  = tid >> 6;
    const int lane = tid & 63;
    const int e = lane & 15, g = lane >> 4;
    float* fb = &fx[wib][0];

    bf16x8 A2[4][2];
    f32x4 b2r[4], wir[4];
    #pragma unroll
    for (int t = 0; t < 4; ++t) {
        #pragma unroll
        for (int ks = 0; ks < 2; ++ks) {
            bf16x8 a;
            #pragma unroll
            for (int j = 0; j < 8; ++j)
                a[j] = f2h(We2[(32 * ks + 8 * g + j) * 64 + 16 * t + e]);
            A2[t][ks] = a;
        }
        #pragma unroll
        for (int r = 0; r < 4; ++r) {
            b2r[t][r] = be2[16 * t + 4 * g + r];
            wir[t][r] = Winf[16 * t + 4 * g + r];
        }
    }
    const float binf0 = binf[0];

    const int gwid = blockIdx.x * 4 + wib;
    const int nw   = gridDim.x * 4;

    for (int tile = gwid; tile < NE / 16; tile += nw) {
        const int eid = tile * 16 + e;
        const int sN = ei[eid];
        const int dN = ei[NE + eid];

        const float dx = x[dN * 3 + 0] - x[sN * 3 + 0];
        const float dy = x[dN * 3 + 1] - x[sN * 3 + 1];
        const float dz = x[dN * 3 + 2] - x[sN * 3 + 2];
        const float dsq = dx * dx + dy * dy + dz * dz;
        const float edis = sigmoidf_(TEMP / (sqrtf(dsq) + 1e-8f));

        bf16x8 B2[2];
        #pragma unroll
        for (int ks = 0; ks < 2; ++ks) {
            const uint4 ut = *(const uint4*)(Pt + (size_t)dN * 64 + 32 * ks + 8 * g);
            const uint4 ub = *(const uint4*)(Pb + (size_t)sN * 64 + 32 * ks + 8 * g);
            union { uint4 u; bf16x8 b; } cvt;
            cvt.u.x = pk_add_relu(ut.x, ub.x);
            cvt.u.y = pk_add_relu(ut.y, ub.y);
            cvt.u.z = pk_add_relu(ut.z, ub.z);
            cvt.u.w = pk_add_relu(ut.w, ub.w);
            B2[ks] = cvt.b;
        }

        f32x4 acc2[4];
        #pragma unroll
        for (int t = 0; t < 4; ++t) {
            acc2[t] = b2r[t];
            #pragma unroll
            for (int ks = 0; ks < 2; ++ks)
                acc2[t] = __builtin_amdgcn_mfma_f32_16x16x32_f16(A2[t][ks], B2[ks], acc2[t], 0, 0, 0);
        }

        float m[4][4];
        float p = 0.f;
        #pragma unroll
        for (int t = 0; t < 4; ++t)
            #pragma unroll
            for (int r = 0; r < 4; ++r) {
                m[t][r] = fmaxf(acc2[t][r], 0.f);
                p = fmaf(m[t][r], wir[t][r], p);
            }
        p += __shfl_xor(p, 16);
        p += __shfl_xor(p, 32);
        const float w = sigmoidf_((p + binf0) * edis);

        #pragma unroll
        for (int t = 0; t < 4; ++t) {
            float4 v;
            v.x = m[t][0] * w; v.y = m[t][1] * w;
            v.z = m[t][2] * w; v.w = m[t][3] * w;
            *(float4*)&fb[e * FSTR + 16 * t + 4 * g] = v;
        }

        #pragma unroll
        for (int i = 0; i < 16; ++i) {
            const int row = __shfl(dN, i);
            const float v = fb[i * FSTR + lane];
            atomicAdd(mi + (size_t)row * 64 + lane, v);
        }
    }
}

// ============ Node kernel: same B2B MFMA + residual + LayerNorm =============
extern "C" __global__ void __launch_bounds__(256, 2)
node_kernel(const float* __restrict__ h, const float* __restrict__ mi_,
            const float* __restrict__ Wn1, const float* __restrict__ bn1,
            const float* __restrict__ Wn2, const float* __restrict__ bn2,
            const float* __restrict__ lng, const float* __restrict__ lnb,
            float* __restrict__ out)
{
    __shared__ unsigned xlds[4][16 * 32];
    const int tid  = threadIdx.x;
    const int wib  = tid >> 6;
    const int lane = tid & 63;
    const int e = lane & 15, g = lane >> 4;
    unsigned* tb = &xlds[wib][0];
    const int sw = (e & 7) << 2;

    bf16x8 A1[4][4], A2[4][2];
    f32x4 b1r[4], b2r[4], gr[4], br[4];
    #pragma unroll
    for (int t = 0; t < 4; ++t) {
        #pragma unroll
        for (int ks = 0; ks < 4; ++ks) {
            bf16x8 a;
            #pragma unroll
            for (int j = 0; j < 8; ++j)
                a[j] = f2bf(Wn1[(32 * ks + 8 * g + j) * 64 + 16 * t + e]);
            A1[t][ks] = a;
        }
        #pragma unroll
        for (int ks = 0; ks < 2; ++ks) {
            bf16x8 a;
            #pragma unroll
            for (int j = 0; j < 8; ++j)
                a[j] = f2bf(Wn2[(32 * ks + 8 * g + j) * 64 + 16 * t + e]);
            A2[t][ks] = a;
        }
        #pragma unroll
        for (int r = 0; r < 4; ++r) {
            b1r[t][r] = bn1[16 * t + 4 * g + r];
            b2r[t][r] = bn2[16 * t + 4 * g + r];
            gr[t][r]  = lng[16 * t + 4 * g + r];
            br[t][r]  = lnb[16 * t + 4 * g + r];
        }
    }

    const int gwid = blockIdx.x * 4 + wib;
    const int nw   = gridDim.x * 4;

    for (int tile = gwid; tile < NN / 16; tile += nw) {
        const int node = tile * 16 + e;

        bf16x8 B1[4];
        #pragma unroll
        for (int ks = 0; ks < 4; ++ks) {
            const float* srcp = (ks < 2) ? mi_ : h;
            const float4* p = (const float4*)(srcp + (size_t)node * 64 + (ks & 1) * 32 + 8 * g);
            const float4 f0 = p[0], f1 = p[1];
            bf16x8 b;
            b[0] = f2bf(f0.x); b[1] = f2bf(f0.y); b[2] = f2bf(f0.z); b[3] = f2bf(f0.w);
            b[4] = f2bf(f1.x); b[5] = f2bf(f1.y); b[6] = f2bf(f1.z); b[7] = f2bf(f1.w);
            B1[ks] = b;
        }

        f32x4 acc1[4];
        #pragma unroll
        for (int t = 0; t < 4; ++t) {
            acc1[t] = b1r[t];
            #pragma unroll
            for (int ks = 0; ks < 4; ++ks)
                acc1[t] = __builtin_amdgcn_mfma_f32_16x16x32_bf16(A1[t][ks], B1[ks], acc1[t], 0, 0, 0);
        }

        #pragma unroll
        for (int t = 0; t < 4; ++t) {
            const float r0 = fmaxf(acc1[t][0], 0.f), r1 = fmaxf(acc1[t][1], 0.f);
            const float r2 = fmaxf(acc1[t][2], 0.f), r3 = fmaxf(acc1[t][3], 0.f);
            tb[e * 32 + ((8 * t + 2 * g + 0) ^ sw)] = pk2(r0, r1);
            tb[e * 32 + ((8 * t + 2 * g + 1) ^ sw)] = pk2(r2, r3);
        }
        bf16x8 B2[2];
        #pragma unroll
        for (int ks = 0; ks < 2; ++ks) {
            union { uint4 u; bf16x8 b; } cvt;
            cvt.u = *(const uint4*)&tb[e * 32 + ((16 * ks + 4 * g) ^ sw)];
            B2[ks] = cvt.b;
        }

        f32x4 acc2[4];
        #pragma unroll
        for (int t = 0; t < 4; ++t) {
            acc2[t] = b2r[t];
            #pragma unroll
            for (int ks = 0; ks < 2; ++ks)
                acc2[t] = __builtin_amdgcn_mfma_f32_16x16x32_bf16(A2[t][ks], B2[ks], acc2[t], 0, 0, 0);
        }

        float z[4][4];
        float s1 = 0.f, s2 = 0.f;
        #pragma unroll
        for (int t = 0; t < 4; ++t) {
            const float4 hres = *(const float4*)(h + (size_t)node * 64 + 16 * t + 4 * g);
            #pragma unroll
            for (int r = 0; r < 4; ++r) {
                z[t][r] = acc2[t][r] + hres[r];
                s1 += z[t][r];
                s2 = fmaf(z[t][r], z[t][r], s2);
            }
        }
        s1 += __shfl_xor(s1, 16); s1 += __shfl_xor(s1, 32);
        s2 += __shfl_xor(s2, 16); s2 += __shfl_xor(s2, 32);
        const float mu   = s1 * (1.0f / 64.0f);
        const float var  = s2 * (1.0f / 64.0f) - mu * mu;
        const float rstd = rsqrtf(var + LNEPS);

        #pragma unroll
        for (int t = 0; t < 4; ++t) {
            float4 o;
            #pragma unroll
            for (int r = 0; r < 4; ++r)
                o[r] = (z[t][r] - mu) * rstd * gr[t][r] + br[t][r];
            *(float4*)(out + (size_t)node * 64 + 16 * t + 4 * g) = o;
        }
    }
}

extern "C" void kernel_launch(void* const* d_in, const int* in_sizes, int n_in,
                              void* d_out, int out_size, void* d_ws, size_t ws_size,
                              hipStream_t stream)
{
    const float* h    = (const float*)d_in[0];
    const float* x    = (const float*)d_in[1];
    const int*   ei   = (const int*)d_in[2];
    const float* We1  = (const float*)d_in[3];
    const float* be1  = (const float*)d_in[4];
    const float* We2  = (const float*)d_in[5];
    const float* be2  = (const float*)d_in[6];
    const float* Winf = (const float*)d_in[7];
    const float* binf = (const float*)d_in[8];
    const float* Wn1  = (const float*)d_in[9];
    const float* bn1  = (const float*)d_in[10];
    const float* Wn2  = (const float*)d_in[11];
    const float* bn2  = (const float*)d_in[12];
    const float* lng  = (const float*)d_in[13];
    const float* lnb  = (const float*)d_in[14];
    float* out = (float*)d_out;

    const size_t mi_bytes = (size_t)NN * HDIM * sizeof(float);          // 25.6 MB
    const size_t p_bytes  = (size_t)NN * HDIM * sizeof(unsigned short); // 12.8 MB
    const size_t sp_bytes = (size_t)NE * sizeof(int2);                  // 12.8 MB
    const size_t se_bytes = (size_t)NE * sizeof(unsigned);              //  6.4 MB
    const size_t c3_bytes = (size_t)NCNT * sizeof(int);                 //  0.4 MB
    const size_t scratch  = se_bytes + 2 * c3_bytes + SCANB2 * sizeof(int);

    const size_t need_base  = mi_bytes + 2 * p_bytes + sp_bytes;        // 64 MB
    const size_t need_noali = need_base + scratch;                      // ~71.3 MB

    if (ws_size >= need_base && mi_bytes >= scratch) {
        char* ws = (char*)d_ws;
        float*          mi    = (float*)ws;              ws += mi_bytes;
        unsigned short* Pt    = (unsigned short*)ws;     ws += p_bytes;
        unsigned short* Pb    = (unsigned short*)ws;     ws += p_bytes;
        int2*           spair = (int2*)ws;               ws += sp_bytes;

        const bool noalias = (ws_size >= need_noali);
        char* mis = noalias ? ws : (char*)mi;
        unsigned* sedge = (unsigned*)mis;
        int*      cnt3  = (int*)(mis + se_bytes);
        int*      off3  = (int*)(mis + se_bytes + c3_bytes);
        int*      bsum  = (int*)(mis + se_bytes + 2 * c3_bytes);

        hipMemcpyAsync(out + (size_t)NN * HDIM, x, (size_t)NN * 3 * sizeof(float),
                       hipMemcpyDeviceToDevice, stream);

        if (noalias) {
            // mi zeroed inside front_kernel (extra blocks) — hidden under pre
            front_kernel<<<NBLK + 512 + ZBLK, 256, 0, stream>>>(h, We1, be1, Pt, Pb, ei, cnt3, mi);
            scanA_kernel<<<SCANB2, 1024, 0, stream>>>(cnt3, off3, bsum);
            scanC_kernel<<<SCANB2, 1024, 0, stream>>>(off3, bsum);
            scatter3_kernel<<<NBLK, 1024, 0, stream>>>(ei, off3, sedge);
            sort2_kernel<<<NB, 256, 0, stream>>>(sedge, off3, spair);
        } else {
            front_kernel<<<NBLK + 512, 256, 0, stream>>>(h, We1, be1, Pt, Pb, ei, cnt3, nullptr);
            scanA_kernel<<<SCANB2, 1024, 0, stream>>>(cnt3, off3, bsum);
            scanC_kernel<<<SCANB2, 1024, 0, stream>>>(off3, bsum);
            scatter3_kernel<<<NBLK, 1024, 0, stream>>>(ei, off3, sedge);
            sort2_kernel<<<NB, 256, 0, stream>>>(sedge, off3, spair);
            hipMemsetAsync(mi, 0, mi_bytes, stream);   // after sort2: frees aliases
        }
        edge_kernel_sorted<<<2048, 256, 0, stream>>>(Pt, Pb, x, spair, We2, be2, Winf, binf, mi);
        node_kernel<<<512, 256, 0, stream>>>(h, mi, Wn1, bn1, Wn2, bn2, lng, lnb, out);
    } else {
        float* mi;
        unsigned short* Pt;
        unsigned short* Pb;
        if (ws_size >= mi_bytes + 2 * p_bytes) {
            mi = (float*)d_ws;
            Pt = (unsigned short*)((char*)d_ws + mi_bytes);
            Pb = (unsigned short*)((char*)d_ws + mi_bytes + p_bytes);
        } else {
            mi = out;
            Pt = (unsigned short*)d_ws;
            Pb = (unsigned short*)((char*)d_ws + p_bytes);
        }

        hipMemsetAsync(mi, 0, mi_bytes, stream);
        hipMemcpyAsync(out + (size_t)NN * HDIM, x, (size_t)NN * 3 * sizeof(float),
                       hipMemcpyDeviceToDevice, stream);

        front_kernel<<<NBLK + 512, 256, 0, stream>>>(h, We1, be1, Pt, Pb, ei,
                                                     (int*)((char*)d_ws), nullptr);
        edge_kernel_unsorted<<<2048, 256, 0, stream>>>(Pt, Pb, x, ei, We2, be2, Winf, binf, mi);
        node_kernel<<<512, 256, 0, stream>>>(h, mi, Wn1, bn1, Wn2, bn2, lng, lnb, out);
    }
}

// Round 14
// 196.526 us; speedup vs baseline: 1.0226x; 1.0226x over previous
//
#include <hip/hip_runtime.h>
#include <hip/hip_bf16.h>
#include <hip/hip_fp16.h>
#include <math.h>

#define HDIM 64
#define NN   100000
#define NE   1600000
#define TEMP 30.0f
#define LNEPS 1e-5f

// bucketing: 64 nodes per bucket; privatized sort over 64 exclusive edge ranges
#define GSH   6
#define GSZ   64
#define NB    1563           // ceil(NN/64) buckets
#define NBLK  64             // privatized hist/scatter blocks (exclusive ranges)
#define EPB   (NE / NBLK)    // 25000 edges per block
#define NCNT  (NB * NBLK)    // 100032 per-(bucket,block) counters
#define SCANB2 98            // ceil(NCNT/1024)
#define FSTR  72             // padded LDS row stride (words): conflict-free b128
#define ZBLK  1563           // mi-zero blocks (4096 floats each)

typedef __attribute__((ext_vector_type(8))) short bf16x8;
typedef __attribute__((ext_vector_type(4))) float f32x4;
typedef _Float16 __attribute__((ext_vector_type(2))) h2t;

__device__ __forceinline__ short f2bf(float f) {
    __hip_bfloat16 b = __float2bfloat16(f);
    short s; __builtin_memcpy(&s, &b, 2); return s;
}
__device__ __forceinline__ unsigned pk2(float lo, float hi) {
    return (unsigned)(unsigned short)f2bf(lo) | ((unsigned)(unsigned short)f2bf(hi) << 16);
}
__device__ __forceinline__ short f2h(float f) {
    __half h = __float2half(f);
    short s; __builtin_memcpy(&s, &h, 2); return s;
}
__device__ __forceinline__ unsigned pk2h(float lo, float hi) {
    return (unsigned)(unsigned short)f2h(lo) | ((unsigned)(unsigned short)f2h(hi) << 16);
}
// packed fp16 add + relu: v_pk_add_f16 + 3-op sign-mask zeroing
__device__ __forceinline__ unsigned pk_add_relu(unsigned a, unsigned b) {
    h2t x, y;
    __builtin_memcpy(&x, &a, 4); __builtin_memcpy(&y, &b, 4);
    h2t r = x + y;
    unsigned u; __builtin_memcpy(&u, &r, 4);
    const unsigned msk = ((u & 0x80008000u) >> 15) * 0xFFFFu;
    return u & ~msk;
}
__device__ __forceinline__ float sigmoidf_(float z) { return 1.0f / (1.0f + __expf(-z)); }

// ---- shared pre-role body (R12-exact): Pt[n]=h@We1_top+be1, Pb[n]=h@We1_bot (fp16) ----
__device__ __forceinline__ void pre_body(int pb, int tid, float* fx4,
                                         const float* __restrict__ h,
                                         const float* __restrict__ We1,
                                         const float* __restrict__ be1,
                                         unsigned short* __restrict__ Pt,
                                         unsigned short* __restrict__ Pb)
{
    const int wib  = tid >> 6;
    const int lane = tid & 63;
    const int e = lane & 15, g = lane >> 4;
    float* fb = fx4 + wib * 1024;
    const int se = ((e & 1) << 4) | ((e >> 1) & 3);

    bf16x8 At[4][2], Ab[4][2];
    f32x4 b1r[4];
    #pragma unroll
    for (int t = 0; t < 4; ++t) {
        #pragma unroll
        for (int ks = 0; ks < 2; ++ks) {
            bf16x8 a, bb;
            #pragma unroll
            for (int j = 0; j < 8; ++j) {
                a[j]  = f2bf(We1[(32 * ks + 8 * g + j) * 64 + 16 * t + e]);
                bb[j] = f2bf(We1[(64 + 32 * ks + 8 * g + j) * 64 + 16 * t + e]);
            }
            At[t][ks] = a; Ab[t][ks] = bb;
        }
        #pragma unroll
        for (int r = 0; r < 4; ++r) b1r[t][r] = be1[16 * t + 4 * g + r];
    }

    const int gwid = pb * 4 + wib;
    const int nw   = 512 * 4;

    for (int tile = gwid; tile < NN / 16; tile += nw) {
        const int node = tile * 16 + e;

        bf16x8 B[2];
        #pragma unroll
        for (int ks = 0; ks < 2; ++ks) {
            const float4* p = (const float4*)(h + (size_t)node * 64 + ks * 32 + 8 * g);
            const float4 f0 = p[0], f1 = p[1];
            bf16x8 bb;
            bb[0] = f2bf(f0.x); bb[1] = f2bf(f0.y); bb[2] = f2bf(f0.z); bb[3] = f2bf(f0.w);
            bb[4] = f2bf(f1.x); bb[5] = f2bf(f1.y); bb[6] = f2bf(f1.z); bb[7] = f2bf(f1.w);
            B[ks] = bb;
        }

        f32x4 aT[4], aB[4];
        #pragma unroll
        for (int t = 0; t < 4; ++t) {
            aT[t] = b1r[t];
            aB[t] = (f32x4){0.f, 0.f, 0.f, 0.f};
            #pragma unroll
            for (int ks = 0; ks < 2; ++ks) {
                aT[t] = __builtin_amdgcn_mfma_f32_16x16x32_bf16(At[t][ks], B[ks], aT[t], 0, 0, 0);
                aB[t] = __builtin_amdgcn_mfma_f32_16x16x32_bf16(Ab[t][ks], B[ks], aB[t], 0, 0, 0);
            }
        }

        #pragma unroll
        for (int t = 0; t < 4; ++t)
            #pragma unroll
            for (int r = 0; r < 4; ++r)
                fb[e * 64 + ((16 * t + 4 * g + r) ^ se)] = aT[t][r];
        #pragma unroll
        for (int q = 0; q < 2; ++q) {
            const int row = q * 8 + (lane >> 3);
            const int sr  = ((row & 1) << 4) | ((row >> 1) & 3);
            const int c0  = (lane & 7) * 8;
            uint4 o;
            o.x = pk2h(fb[row * 64 + ((c0 + 0) ^ sr)], fb[row * 64 + ((c0 + 1) ^ sr)]);
            o.y = pk2h(fb[row * 64 + ((c0 + 2) ^ sr)], fb[row * 64 + ((c0 + 3) ^ sr)]);
            o.z = pk2h(fb[row * 64 + ((c0 + 4) ^ sr)], fb[row * 64 + ((c0 + 5) ^ sr)]);
            o.w = pk2h(fb[row * 64 + ((c0 + 6) ^ sr)], fb[row * 64 + ((c0 + 7) ^ sr)]);
            *(uint4*)((char*)Pt + (size_t)tile * 2048 + q * 1024 + lane * 16) = o;
        }

        #pragma unroll
        for (int t = 0; t < 4; ++t)
            #pragma unroll
            for (int r = 0; r < 4; ++r)
                fb[e * 64 + ((16 * t + 4 * g + r) ^ se)] = aB[t][r];
        #pragma unroll
        for (int q = 0; q < 2; ++q) {
            const int row = q * 8 + (lane >> 3);
            const int sr  = ((row & 1) << 4) | ((row >> 1) & 3);
            const int c0  = (lane & 7) * 8;
            uint4 o;
            o.x = pk2h(fb[row * 64 + ((c0 + 0) ^ sr)], fb[row * 64 + ((c0 + 1) ^ sr)]);
            o.y = pk2h(fb[row * 64 + ((c0 + 2) ^ sr)], fb[row * 64 + ((c0 + 3) ^ sr)]);
            o.z = pk2h(fb[row * 64 + ((c0 + 4) ^ sr)], fb[row * 64 + ((c0 + 5) ^ sr)]);
            o.w = pk2h(fb[row * 64 + ((c0 + 6) ^ sr)], fb[row * 64 + ((c0 + 7) ^ sr)]);
            *(uint4*)((char*)Pb + (size_t)tile * 2048 + q * 1024 + lane * 16) = o;
        }
    }
}

// ---- shared sort2-role body (R12-exact) ----
__device__ __forceinline__ void sort2_body(int b, int tid, int* hist, int* base, int* curs,
                                           const unsigned* __restrict__ sedge,
                                           const int* __restrict__ off3,
                                           int2* __restrict__ spair)
{
    const int r0 = off3[b * NBLK];
    const int r1 = (b == NB - 1) ? NE : off3[(b + 1) * NBLK];

    if (tid < GSZ) hist[tid] = 0;
    __syncthreads();
    for (int i = r0 + tid; i < r1; i += 256)
        atomicAdd(&hist[(sedge[i] >> 17) & (GSZ - 1)], 1);
    __syncthreads();
    if (tid == 0) {
        int run = 0;
        for (int j = 0; j < GSZ; ++j) { base[j] = run; run += hist[j]; }
    }
    __syncthreads();
    if (tid < GSZ) curs[tid] = base[tid];
    __syncthreads();
    for (int i = r0 + tid; i < r1; i += 256) {
        const unsigned pk = sedge[i];
        const int dl = (pk >> 17) & (GSZ - 1);
        const int pos = r0 + atomicAdd(&curs[dl], 1);
        spair[pos] = make_int2((int)(pk & 0x1FFFFu), (b << GSH) | dl);
    }
}

// ============ hist kernel (standalone, 64 blocks): zero global atomics ============
extern "C" __global__ void __launch_bounds__(256)
hist_kernel(const int* __restrict__ ei, int* __restrict__ cnt3)
{
    __shared__ int hbin[NB];
    const int b = blockIdx.x;
    const int tid = threadIdx.x;
    for (int k = tid; k < NB; k += 256) hbin[k] = 0;
    __syncthreads();
    const int i0 = b * EPB;
    for (int i = i0 + tid; i < i0 + EPB; i += 256)
        atomicAdd(&hbin[ei[NE + i] >> GSH], 1);
    __syncthreads();
    for (int k = tid; k < NB; k += 256)
        cnt3[k * NBLK + b] = hbin[k];
}

// ============ front kernel (aliased fallback path: hist + pre fused) ============
extern "C" __global__ void __launch_bounds__(256, 2)
front_kernel(const float* __restrict__ h,
             const float* __restrict__ We1, const float* __restrict__ be1,
             unsigned short* __restrict__ Pt, unsigned short* __restrict__ Pb,
             const int* __restrict__ ei, int* __restrict__ cnt3)
{
    __shared__ float fx[4][1024];
    const int b = blockIdx.x;
    if (b < NBLK) {
        int* hbin = (int*)&fx[0][0];
        const int tid = threadIdx.x;
        for (int k = tid; k < NB; k += 256) hbin[k] = 0;
        __syncthreads();
        const int i0 = b * EPB;
        for (int i = i0 + tid; i < i0 + EPB; i += 256)
            atomicAdd(&hbin[ei[NE + i] >> GSH], 1);
        __syncthreads();
        for (int k = tid; k < NB; k += 256)
            cnt3[k * NBLK + b] = hbin[k];
        return;
    }
    pre_body(b - NBLK, threadIdx.x, &fx[0][0], h, We1, be1, Pt, Pb);
}

// ============ Hierarchical exclusive scan of cnt3[NCNT] -> off3 ============
extern "C" __global__ void __launch_bounds__(1024)
scanA_kernel(const int* __restrict__ cnt3, int* __restrict__ off3, int* __restrict__ bsum)
{
    __shared__ int sh[1024];
    const int t = threadIdx.x;
    const int i = blockIdx.x * 1024 + t;
    const int v = (i < NCNT) ? cnt3[i] : 0;
    sh[t] = v;
    __syncthreads();
    for (int off = 1; off < 1024; off <<= 1) {
        const int u = (t >= off) ? sh[t - off] : 0;
        __syncthreads();
        sh[t] += u;
        __syncthreads();
    }
    if (i < NCNT) off3[i] = sh[t] - v;
    if (t == 1023) bsum[blockIdx.x] = sh[1023];
}

extern "C" __global__ void __launch_bounds__(128)
scanB_kernel(int* __restrict__ bsum)
{
    __shared__ int sh[128];
    const int t = threadIdx.x;
    const int v = (t < SCANB2) ? bsum[t] : 0;
    sh[t] = v;
    __syncthreads();
    for (int off = 1; off < 128; off <<= 1) {
        const int u = (t >= off) ? sh[t - off] : 0;
        __syncthreads();
        sh[t] += u;
        __syncthreads();
    }
    if (t < SCANB2) bsum[t] = sh[t] - v;
}

extern "C" __global__ void __launch_bounds__(1024)
scanC_kernel(int* __restrict__ off3, const int* __restrict__ bsum)
{
    const int i = blockIdx.x * 1024 + threadIdx.x;
    if (i < NCNT) off3[i] += bsum[blockIdx.x];
}

// ============ Privatized scatter: LDS cursors, zero global atomics ============
extern "C" __global__ void __launch_bounds__(1024)
scatter3_kernel(const int* __restrict__ ei, const int* __restrict__ off3,
                unsigned* __restrict__ sedge)
{
    __shared__ int cur[NB];
    const int b   = blockIdx.x;                  // grid must be NBLK
    const int tid = threadIdx.x;
    for (int k = tid; k < NB; k += 1024) cur[k] = off3[k * NBLK + b];
    __syncthreads();
    const int i0 = b * EPB;
    for (int i = i0 + tid; i < i0 + EPB; i += 1024) {
        const int s = ei[i];
        const int d = ei[NE + i];
        const int pos = atomicAdd(&cur[d >> GSH], 1);   // LDS atomic
        sedge[pos] = (unsigned)s | ((unsigned)(d & (GSZ - 1)) << 17);
    }
}

// ============ sort2 (standalone, aliased fallback path) ============
extern "C" __global__ void __launch_bounds__(256)
sort2_kernel(const unsigned* __restrict__ sedge, const int* __restrict__ off3,
             int2* __restrict__ spair)
{
    __shared__ int hist[GSZ], base[GSZ], curs[GSZ];
    sort2_body(blockIdx.x, threadIdx.x, hist, base, curs, sedge, off3, spair);
}

// ============ tail kernel: sort2 (NB) || pre (512) || mi-zero (ZBLK) ============
extern "C" __global__ void __launch_bounds__(256, 2)
tail_kernel(const unsigned* __restrict__ sedge, const int* __restrict__ off3,
            int2* __restrict__ spair,
            const float* __restrict__ h,
            const float* __restrict__ We1, const float* __restrict__ be1,
            unsigned short* __restrict__ Pt, unsigned short* __restrict__ Pb,
            float* __restrict__ mi)
{
    __shared__ float fx[4][1024];
    __shared__ int hist[GSZ], base[GSZ], curs[GSZ];
    const int b = blockIdx.x;

    if (b < NB) {
        sort2_body(b, threadIdx.x, hist, base, curs, sedge, off3, spair);
        return;
    }
    if (b < NB + 512) {
        pre_body(b - NB, threadIdx.x, &fx[0][0], h, We1, be1, Pt, Pb);
        return;
    }
    // mi-zero role
    const int zb = b - NB - 512;
    const size_t base4 = (size_t)zb * 1024;       // float4 units
    const size_t tot4  = (size_t)NN * 16;
    float4* dst = (float4*)mi;
    for (int i = threadIdx.x; i < 1024; i += 256) {
        const size_t idx = base4 + i;
        if (idx < tot4) dst[idx] = (float4){0.f, 0.f, 0.f, 0.f};
    }
}

// ============ Edge kernel (sorted): R12-exact register-run accumulation ====
extern "C" __global__ void __launch_bounds__(256, 2)
edge_kernel_sorted(const unsigned short* __restrict__ Pt, const unsigned short* __restrict__ Pb,
                   const float* __restrict__ x, const int2* __restrict__ spair,
                   const float* __restrict__ We2, const float* __restrict__ be2,
                   const float* __restrict__ Winf, const float* __restrict__ binf,
                   float* __restrict__ mi)
{
    __shared__ float fx[4][16 * FSTR];   // 18 KB
    const int tid  = threadIdx.x;
    const int wib  = tid >> 6;
    const int lane = tid & 63;
    const int e = lane & 15, g = lane >> 4;
    float* fb = &fx[wib][0];

    bf16x8 A2[4][2];                        // fp16 fragments
    f32x4 b2r[4], wir[4];
    #pragma unroll
    for (int t = 0; t < 4; ++t) {
        #pragma unroll
        for (int ks = 0; ks < 2; ++ks) {
            bf16x8 a;
            #pragma unroll
            for (int j = 0; j < 8; ++j)
                a[j] = f2h(We2[(32 * ks + 8 * g + j) * 64 + 16 * t + e]);
            A2[t][ks] = a;
        }
        #pragma unroll
        for (int r = 0; r < 4; ++r) {
            b2r[t][r] = be2[16 * t + 4 * g + r];
            wir[t][r] = Winf[16 * t + 4 * g + r];
        }
    }
    const float binf0 = binf[0];

    const int NT     = NE / 16;
    const int nwaves = gridDim.x * 4;
    const int gwid   = blockIdx.x * 4 + wib;
    const int chunk  = (NT + nwaves - 1) / nwaves;
    const int t0 = gwid * chunk;
    const int t1 = (t0 + chunk < NT) ? t0 + chunk : NT;

    float racc  = 0.f;
    int   rrow  = -1;

    for (int tile = t0; tile < t1; ++tile) {
        const int eid = tile * 16 + e;
        const int2 sd = spair[eid];
        const int sN = sd.x;
        const int dN = sd.y;

        const float dx = x[dN * 3 + 0] - x[sN * 3 + 0];
        const float dy = x[dN * 3 + 1] - x[sN * 3 + 1];
        const float dz = x[dN * 3 + 2] - x[sN * 3 + 2];
        const float dsq = dx * dx + dy * dy + dz * dz;
        const float edis = sigmoidf_(TEMP / (sqrtf(dsq) + 1e-8f));

        bf16x8 B2[2];
        #pragma unroll
        for (int ks = 0; ks < 2; ++ks) {
            const uint4 ut = *(const uint4*)(Pt + (size_t)dN * 64 + 32 * ks + 8 * g);
            const uint4 ub = *(const uint4*)(Pb + (size_t)sN * 64 + 32 * ks + 8 * g);
            union { uint4 u; bf16x8 b; } cvt;
            cvt.u.x = pk_add_relu(ut.x, ub.x);
            cvt.u.y = pk_add_relu(ut.y, ub.y);
            cvt.u.z = pk_add_relu(ut.z, ub.z);
            cvt.u.w = pk_add_relu(ut.w, ub.w);
            B2[ks] = cvt.b;
        }

        f32x4 acc2[4];
        #pragma unroll
        for (int t = 0; t < 4; ++t) {
            acc2[t] = b2r[t];
            #pragma unroll
            for (int ks = 0; ks < 2; ++ks)
                acc2[t] = __builtin_amdgcn_mfma_f32_16x16x32_f16(A2[t][ks], B2[ks], acc2[t], 0, 0, 0);
        }

        float m[4][4];
        float p = 0.f;
        #pragma unroll
        for (int t = 0; t < 4; ++t)
            #pragma unroll
            for (int r = 0; r < 4; ++r) {
                m[t][r] = fmaxf(acc2[t][r], 0.f);
                p = fmaf(m[t][r], wir[t][r], p);
            }
        p += __shfl_xor(p, 16);
        p += __shfl_xor(p, 32);
        const float w = sigmoidf_((p + binf0) * edis);

        #pragma unroll
        for (int t = 0; t < 4; ++t) {
            float4 v;
            v.x = m[t][0] * w; v.y = m[t][1] * w;
            v.z = m[t][2] * w; v.w = m[t][3] * w;
            *(float4*)&fb[e * FSTR + 16 * t + 4 * g] = v;
        }

        #pragma unroll
        for (int i = 0; i < 16; ++i) {
            const int row = __builtin_amdgcn_readlane(dN, i);
            const float v = fb[i * FSTR + lane];
            if (row != rrow) {
                if (rrow >= 0) atomicAdd(mi + (size_t)rrow * 64 + lane, racc);
                rrow = row; racc = v;
            } else {
                racc += v;
            }
        }
    }
    if (rrow >= 0) atomicAdd(mi + (size_t)rrow * 64 + lane, racc);
}

// ============ Edge kernel (unsorted fallback, small-ws path) ============
extern "C" __global__ void __launch_bounds__(256, 2)
edge_kernel_unsorted(const unsigned short* __restrict__ Pt, const unsigned short* __restrict__ Pb,
                     const float* __restrict__ x, const int* __restrict__ ei,
                     const float* __restrict__ We2, const float* __restrict__ be2,
                     const float* __restrict__ Winf, const float* __restrict__ binf,
                     float* __restrict__ mi)
{
    __shared__ float fx[4][16 * FSTR];
    const int tid  = threadIdx.x;
    const int wib  = tid >> 6;
    const int lane = tid & 63;
    const int e = lane & 15, g = lane >> 4;
    float* fb = &fx[wib][0];

    bf16x8 A2[4][2];
    f32x4 b2r[4], wir[4];
    #pragma unroll
    for (int t = 0; t < 4; ++t) {
        #pragma unroll
        for (int ks = 0; ks < 2; ++ks) {
            bf16x8 a;
            #pragma unroll
            for (int j = 0; j < 8; ++j)
                a[j] = f2h(We2[(32 * ks + 8 * g + j) * 64 + 16 * t + e]);
            A2[t][ks] = a;
        }
        #pragma unroll
        for (int r = 0; r < 4; ++r) {
            b2r[t][r] = be2[16 * t + 4 * g + r];
            wir[t][r] = Winf[16 * t + 4 * g + r];
        }
    }
    const float binf0 = binf[0];

    const int gwid = blockIdx.x * 4 + wib;
    const int nw   = gridDim.x * 4;

    for (int tile = gwid; tile < NE / 16; tile += nw) {
        const int eid = tile * 16 + e;
        const int sN = ei[eid];
        const int dN = ei[NE + eid];

        const float dx = x[dN * 3 + 0] - x[sN * 3 + 0];
        const float dy = x[dN * 3 + 1] - x[sN * 3 + 1];
        const float dz = x[dN * 3 + 2] - x[sN * 3 + 2];
        const float dsq = dx * dx + dy * dy + dz * dz;
        const float edis = sigmoidf_(TEMP / (sqrtf(dsq) + 1e-8f));

        bf16x8 B2[2];
        #pragma unroll
        for (int ks = 0; ks < 2; ++ks) {
            const uint4 ut = *(const uint4*)(Pt + (size_t)dN * 64 + 32 * ks + 8 * g);
            const uint4 ub = *(const uint4*)(Pb + (size_t)sN * 64 + 32 * ks + 8 * g);
            union { uint4 u; bf16x8 b; } cvt;
            cvt.u.x = pk_add_relu(ut.x, ub.x);
            cvt.u.y = pk_add_relu(ut.y, ub.y);
            cvt.u.z = pk_add_relu(ut.z, ub.z);
            cvt.u.w = pk_add_relu(ut.w, ub.w);
            B2[ks] = cvt.b;
        }

        f32x4 acc2[4];
        #pragma unroll
        for (int t = 0; t < 4; ++t) {
            acc2[t] = b2r[t];
            #pragma unroll
            for (int ks = 0; ks < 2; ++ks)
                acc2[t] = __builtin_amdgcn_mfma_f32_16x16x32_f16(A2[t][ks], B2[ks], acc2[t], 0, 0, 0);
        }

        float m[4][4];
        float p = 0.f;
        #pragma unroll
        for (int t = 0; t < 4; ++t)
            #pragma unroll
            for (int r = 0; r < 4; ++r) {
                m[t][r] = fmaxf(acc2[t][r], 0.f);
                p = fmaf(m[t][r], wir[t][r], p);
            }
        p += __shfl_xor(p, 16);
        p += __shfl_xor(p, 32);
        const float w = sigmoidf_((p + binf0) * edis);

        #pragma unroll
        for (int t = 0; t < 4; ++t) {
            float4 v;
            v.x = m[t][0] * w; v.y = m[t][1] * w;
            v.z = m[t][2] * w; v.w = m[t][3] * w;
            *(float4*)&fb[e * FSTR + 16 * t + 4 * g] = v;
        }

        #pragma unroll
        for (int i = 0; i < 16; ++i) {
            const int row = __shfl(dN, i);
            const float v = fb[i * FSTR + lane];
            atomicAdd(mi + (size_t)row * 64 + lane, v);
        }
    }
}

// ============ Node kernel: same B2B MFMA + residual + LayerNorm =============
extern "C" __global__ void __launch_bounds__(256, 2)
node_kernel(const float* __restrict__ h, const float* __restrict__ mi_,
            const float* __restrict__ Wn1, const float* __restrict__ bn1,
            const float* __restrict__ Wn2, const float* __restrict__ bn2,
            const float* __restrict__ lng, const float* __restrict__ lnb,
            float* __restrict__ out)
{
    __shared__ unsigned xlds[4][16 * 32];
    const int tid  = threadIdx.x;
    const int wib  = tid >> 6;
    const int lane = tid & 63;
    const int e = lane & 15, g = lane >> 4;
    unsigned* tb = &xlds[wib][0];
    const int sw = (e & 7) << 2;

    bf16x8 A1[4][4], A2[4][2];
    f32x4 b1r[4], b2r[4], gr[4], br[4];
    #pragma unroll
    for (int t = 0; t < 4; ++t) {
        #pragma unroll
        for (int ks = 0; ks < 4; ++ks) {
            bf16x8 a;
            #pragma unroll
            for (int j = 0; j < 8; ++j)
                a[j] = f2bf(Wn1[(32 * ks + 8 * g + j) * 64 + 16 * t + e]);
            A1[t][ks] = a;
        }
        #pragma unroll
        for (int ks = 0; ks < 2; ++ks) {
            bf16x8 a;
            #pragma unroll
            for (int j = 0; j < 8; ++j)
                a[j] = f2bf(Wn2[(32 * ks + 8 * g + j) * 64 + 16 * t + e]);
            A2[t][ks] = a;
        }
        #pragma unroll
        for (int r = 0; r < 4; ++r) {
            b1r[t][r] = bn1[16 * t + 4 * g + r];
            b2r[t][r] = bn2[16 * t + 4 * g + r];
            gr[t][r]  = lng[16 * t + 4 * g + r];
            br[t][r]  = lnb[16 * t + 4 * g + r];
        }
    }

    const int gwid = blockIdx.x * 4 + wib;
    const int nw   = gridDim.x * 4;

    for (int tile = gwid; tile < NN / 16; tile += nw) {
        const int node = tile * 16 + e;

        bf16x8 B1[4];
        #pragma unroll
        for (int ks = 0; ks < 4; ++ks) {
            const float* srcp = (ks < 2) ? mi_ : h;
            const float4* p = (const float4*)(srcp + (size_t)node * 64 + (ks & 1) * 32 + 8 * g);
            const float4 f0 = p[0], f1 = p[1];
            bf16x8 b;
            b[0] = f2bf(f0.x); b[1] = f2bf(f0.y); b[2] = f2bf(f0.z); b[3] = f2bf(f0.w);
            b[4] = f2bf(f1.x); b[5] = f2bf(f1.y); b[6] = f2bf(f1.z); b[7] = f2bf(f1.w);
            B1[ks] = b;
        }

        f32x4 acc1[4];
        #pragma unroll
        for (int t = 0; t < 4; ++t) {
            acc1[t] = b1r[t];
            #pragma unroll
            for (int ks = 0; ks < 4; ++ks)
                acc1[t] = __builtin_amdgcn_mfma_f32_16x16x32_bf16(A1[t][ks], B1[ks], acc1[t], 0, 0, 0);
        }

        #pragma unroll
        for (int t = 0; t < 4; ++t) {
            const float r0 = fmaxf(acc1[t][0], 0.f), r1 = fmaxf(acc1[t][1], 0.f);
            const float r2 = fmaxf(acc1[t][2], 0.f), r3 = fmaxf(acc1[t][3], 0.f);
            tb[e * 32 + ((8 * t + 2 * g + 0) ^ sw)] = pk2(r0, r1);
            tb[e * 32 + ((8 * t + 2 * g + 1) ^ sw)] = pk2(r2, r3);
        }
        bf16x8 B2[2];
        #pragma unroll
        for (int ks = 0; ks < 2; ++ks) {
            union { uint4 u; bf16x8 b; } cvt;
            cvt.u = *(const uint4*)&tb[e * 32 + ((16 * ks + 4 * g) ^ sw)];
            B2[ks] = cvt.b;
        }

        f32x4 acc2[4];
        #pragma unroll
        for (int t = 0; t < 4; ++t) {
            acc2[t] = b2r[t];
            #pragma unroll
            for (int ks = 0; ks < 2; ++ks)
                acc2[t] = __builtin_amdgcn_mfma_f32_16x16x32_bf16(A2[t][ks], B2[ks], acc2[t], 0, 0, 0);
        }

        float z[4][4];
        float s1 = 0.f, s2 = 0.f;
        #pragma unroll
        for (int t = 0; t < 4; ++t) {
            const float4 hres = *(const float4*)(h + (size_t)node * 64 + 16 * t + 4 * g);
            #pragma unroll
            for (int r = 0; r < 4; ++r) {
                z[t][r] = acc2[t][r] + hres[r];
                s1 += z[t][r];
                s2 = fmaf(z[t][r], z[t][r], s2);
            }
        }
        s1 += __shfl_xor(s1, 16); s1 += __shfl_xor(s1, 32);
        s2 += __shfl_xor(s2, 16); s2 += __shfl_xor(s2, 32);
        const float mu   = s1 * (1.0f / 64.0f);
        const float var  = s2 * (1.0f / 64.0f) - mu * mu;
        const float rstd = rsqrtf(var + LNEPS);

        #pragma unroll
        for (int t = 0; t < 4; ++t) {
            float4 o;
            #pragma unroll
            for (int r = 0; r < 4; ++r)
                o[r] = (z[t][r] - mu) * rstd * gr[t][r] + br[t][r];
            *(float4*)(out + (size_t)node * 64 + 16 * t + 4 * g) = o;
        }
    }
}

extern "C" void kernel_launch(void* const* d_in, const int* in_sizes, int n_in,
                              void* d_out, int out_size, void* d_ws, size_t ws_size,
                              hipStream_t stream)
{
    const float* h    = (const float*)d_in[0];
    const float* x    = (const float*)d_in[1];
    const int*   ei   = (const int*)d_in[2];
    const float* We1  = (const float*)d_in[3];
    const float* be1  = (const float*)d_in[4];
    const float* We2  = (const float*)d_in[5];
    const float* be2  = (const float*)d_in[6];
    const float* Winf = (const float*)d_in[7];
    const float* binf = (const float*)d_in[8];
    const float* Wn1  = (const float*)d_in[9];
    const float* bn1  = (const float*)d_in[10];
    const float* Wn2  = (const float*)d_in[11];
    const float* bn2  = (const float*)d_in[12];
    const float* lng  = (const float*)d_in[13];
    const float* lnb  = (const float*)d_in[14];
    float* out = (float*)d_out;

    const size_t mi_bytes = (size_t)NN * HDIM * sizeof(float);          // 25.6 MB
    const size_t p_bytes  = (size_t)NN * HDIM * sizeof(unsigned short); // 12.8 MB
    const size_t sp_bytes = (size_t)NE * sizeof(int2);                  // 12.8 MB
    const size_t se_bytes = (size_t)NE * sizeof(unsigned);              //  6.4 MB
    const size_t c3_bytes = (size_t)NCNT * sizeof(int);                 //  0.4 MB
    const size_t scratch  = se_bytes + 2 * c3_bytes + SCANB2 * sizeof(int);

    const size_t need_base  = mi_bytes + 2 * p_bytes + sp_bytes;        // 64 MB
    const size_t need_noali = need_base + scratch;                      // ~71.3 MB

    if (ws_size >= need_base && mi_bytes >= scratch) {
        char* ws = (char*)d_ws;
        float*          mi    = (float*)ws;              ws += mi_bytes;
        unsigned short* Pt    = (unsigned short*)ws;     ws += p_bytes;
        unsigned short* Pb    = (unsigned short*)ws;     ws += p_bytes;
        int2*           spair = (int2*)ws;               ws += sp_bytes;

        const bool noalias = (ws_size >= need_noali);
        char* mis = noalias ? ws : (char*)mi;
        unsigned* sedge = (unsigned*)mis;
        int*      cnt3  = (int*)(mis + se_bytes);
        int*      off3  = (int*)(mis + se_bytes + c3_bytes);
        int*      bsum  = (int*)(mis + se_bytes + 2 * c3_bytes);

        hipMemcpyAsync(out + (size_t)NN * HDIM, x, (size_t)NN * 3 * sizeof(float),
                       hipMemcpyDeviceToDevice, stream);

        if (noalias) {
            // pre + mi-zero overlap sort2 in the tail launch; hist stands alone
            hist_kernel<<<NBLK, 256, 0, stream>>>(ei, cnt3);
            scanA_kernel<<<SCANB2, 1024, 0, stream>>>(cnt3, off3, bsum);
            scanB_kernel<<<1, 128, 0, stream>>>(bsum);
            scanC_kernel<<<SCANB2, 1024, 0, stream>>>(off3, bsum);
            scatter3_kernel<<<NBLK, 1024, 0, stream>>>(ei, off3, sedge);
            tail_kernel<<<NB + 512 + ZBLK, 256, 0, stream>>>(sedge, off3, spair,
                                                             h, We1, be1, Pt, Pb, mi);
        } else {
            // aliased fallback: R12-exact flow
            front_kernel<<<NBLK + 512, 256, 0, stream>>>(h, We1, be1, Pt, Pb, ei, cnt3);
            scanA_kernel<<<SCANB2, 1024, 0, stream>>>(cnt3, off3, bsum);
            scanB_kernel<<<1, 128, 0, stream>>>(bsum);
            scanC_kernel<<<SCANB2, 1024, 0, stream>>>(off3, bsum);
            scatter3_kernel<<<NBLK, 1024, 0, stream>>>(ei, off3, sedge);
            sort2_kernel<<<NB, 256, 0, stream>>>(sedge, off3, spair);
            hipMemsetAsync(mi, 0, mi_bytes, stream);
        }
        edge_kernel_sorted<<<2048, 256, 0, stream>>>(Pt, Pb, x, spair, We2, be2, Winf, binf, mi);
        node_kernel<<<512, 256, 0, stream>>>(h, mi, Wn1, bn1, Wn2, bn2, lng, lnb, out);
    } else {
        float* mi;
        unsigned short* Pt;
        unsigned short* Pb;
        if (ws_size >= mi_bytes + 2 * p_bytes) {
            mi = (float*)d_ws;
            Pt = (unsigned short*)((char*)d_ws + mi_bytes);
            Pb = (unsigned short*)((char*)d_ws + mi_bytes + p_bytes);
        } else {
            mi = out;
            Pt = (unsigned short*)d_ws;
            Pb = (unsigned short*)((char*)d_ws + p_bytes);
        }

        hipMemsetAsync(mi, 0, mi_bytes, stream);
        hipMemcpyAsync(out + (size_t)NN * HDIM, x, (size_t)NN * 3 * sizeof(float),
                       hipMemcpyDeviceToDevice, stream);

        front_kernel<<<NBLK + 512, 256, 0, stream>>>(h, We1, be1, Pt, Pb, ei,
                                                     (int*)((char*)d_ws));
        edge_kernel_unsorted<<<2048, 256, 0, stream>>>(Pt, Pb, x, ei, We2, be2, Winf, binf, mi);
        node_kernel<<<512, 256, 0, stream>>>(h, mi, Wn1, bn1, Wn2, bn2, lng, lnb, out);
    }
}

// Round 16
// 191.787 us; speedup vs baseline: 1.0479x; 1.0247x over previous
//
#include <hip/hip_runtime.h>
#include <hip/hip_bf16.h>
#include <hip/hip_fp16.h>
#include <math.h>

#define HDIM 64
#define NN   100000
#define NE   1600000
#define TEMP 30.0f
#define LNEPS 1e-5f

// bucketing: 64 nodes per bucket; privatized sort over 64 exclusive edge ranges
#define GSH   6
#define GSZ   64
#define NB    1563           // ceil(NN/64) buckets
#define NBLK  64             // privatized hist/scatter blocks (exclusive ranges)
#define EPB   (NE / NBLK)    // 25000 edges per block
#define NCNT  (NB * NBLK)    // 100032 per-(bucket,block) counters
#define SCANB2 98            // ceil(NCNT/1024)
#define FSTR  72             // padded LDS row stride (words): conflict-free b128

typedef __attribute__((ext_vector_type(8))) short bf16x8;
typedef __attribute__((ext_vector_type(4))) float f32x4;
typedef _Float16 __attribute__((ext_vector_type(2))) h2t;

__device__ __forceinline__ short f2h(float f) {
    __half h = __float2half(f);
    short s; __builtin_memcpy(&s, &h, 2); return s;
}
// HW packed 2xf32 -> 2xf16 (RTZ), single instruction, compiler-scheduled builtin.
// NOTE: builtin returns an __fp16-element vector; bind with auto and memcpy
// (direct assignment to a _Float16 vector is a type error).
__device__ __forceinline__ unsigned pkrtz(float lo, float hi) {
    auto r = __builtin_amdgcn_cvt_pkrtz(lo, hi);
    unsigned u; __builtin_memcpy(&u, &r, 4); return u;
}
// packed fp16 add + relu: v_pk_add_f16 + 3-op sign-mask zeroing
__device__ __forceinline__ unsigned pk_add_relu(unsigned a, unsigned b) {
    h2t x, y;
    __builtin_memcpy(&x, &a, 4); __builtin_memcpy(&y, &b, 4);
    h2t r = x + y;
    unsigned u; __builtin_memcpy(&u, &r, 4);
    const unsigned msk = ((u & 0x80008000u) >> 15) * 0xFFFFu;
    return u & ~msk;
}
__device__ __forceinline__ float sigmoidf_(float z) { return 1.0f / (1.0f + __expf(-z)); }

// ============ Front kernel: privatized hist (64 blocks) || pre (512 blocks) ====
// hist role: LDS histogram of its exclusive 25K-edge range -> non-atomic store.
// pre role: Pt[n]=h@We1_top+be1, Pb[n]=h@We1_bot, FP16 rows (128 B), all-f16 GEMM.
extern "C" __global__ void __launch_bounds__(256, 2)
front_kernel(const float* __restrict__ h,
             const float* __restrict__ We1, const float* __restrict__ be1,
             unsigned short* __restrict__ Pt, unsigned short* __restrict__ Pb,
             const int* __restrict__ ei, int* __restrict__ cnt3)
{
    __shared__ float fx[4][1024];    // 16 KB: pre transpose buffers / hist bins
    const int b = blockIdx.x;

    if (b < NBLK) {
        int* hbin = (int*)&fx[0][0];           // 1563 ints (6.25 KB)
        const int tid = threadIdx.x;
        for (int k = tid; k < NB; k += 256) hbin[k] = 0;
        __syncthreads();
        const int i0 = b * EPB;
        for (int i = i0 + tid; i < i0 + EPB; i += 256)
            atomicAdd(&hbin[ei[NE + i] >> GSH], 1);
        __syncthreads();
        for (int k = tid; k < NB; k += 256)
            cnt3[k * NBLK + b] = hbin[k];      // exclusive slot: plain store
        return;
    }

    // ---- pre role (all-f16: HW pkrtz converts, f16 MFMA) ----
    const int pb   = b - NBLK;
    const int tid  = threadIdx.x;
    const int wib  = tid >> 6;
    const int lane = tid & 63;
    const int e = lane & 15, g = lane >> 4;
    float* fb = &fx[wib][0];
    const int se = ((e & 1) << 4) | ((e >> 1) & 3);

    bf16x8 At[4][2], Ab[4][2];   // f16 payload
    f32x4 b1r[4];
    #pragma unroll
    for (int t = 0; t < 4; ++t) {
        #pragma unroll
        for (int ks = 0; ks < 2; ++ks) {
            bf16x8 a, bb;
            #pragma unroll
            for (int j = 0; j < 8; ++j) {
                a[j]  = f2h(We1[(32 * ks + 8 * g + j) * 64 + 16 * t + e]);
                bb[j] = f2h(We1[(64 + 32 * ks + 8 * g + j) * 64 + 16 * t + e]);
            }
            At[t][ks] = a; Ab[t][ks] = bb;
        }
        #pragma unroll
        for (int r = 0; r < 4; ++r) b1r[t][r] = be1[16 * t + 4 * g + r];
    }

    const int gwid = pb * 4 + wib;
    const int nw   = 512 * 4;

    for (int tile = gwid; tile < NN / 16; tile += nw) {
        const int node = tile * 16 + e;

        bf16x8 B[2];
        #pragma unroll
        for (int ks = 0; ks < 2; ++ks) {
            const float4* p = (const float4*)(h + (size_t)node * 64 + ks * 32 + 8 * g);
            const float4 f0 = p[0], f1 = p[1];
            union { uint4 u; bf16x8 b; } cvt;
            cvt.u.x = pkrtz(f0.x, f0.y); cvt.u.y = pkrtz(f0.z, f0.w);
            cvt.u.z = pkrtz(f1.x, f1.y); cvt.u.w = pkrtz(f1.z, f1.w);
            B[ks] = cvt.b;
        }

        f32x4 aT[4], aB[4];
        #pragma unroll
        for (int t = 0; t < 4; ++t) {
            aT[t] = b1r[t];
            aB[t] = (f32x4){0.f, 0.f, 0.f, 0.f};
            #pragma unroll
            for (int ks = 0; ks < 2; ++ks) {
                aT[t] = __builtin_amdgcn_mfma_f32_16x16x32_f16(At[t][ks], B[ks], aT[t], 0, 0, 0);
                aB[t] = __builtin_amdgcn_mfma_f32_16x16x32_f16(Ab[t][ks], B[ks], aB[t], 0, 0, 0);
            }
        }

        #pragma unroll
        for (int t = 0; t < 4; ++t)
            #pragma unroll
            for (int r = 0; r < 4; ++r)
                fb[e * 64 + ((16 * t + 4 * g + r) ^ se)] = aT[t][r];
        #pragma unroll
        for (int q = 0; q < 2; ++q) {
            const int row = q * 8 + (lane >> 3);
            const int sr  = ((row & 1) << 4) | ((row >> 1) & 3);
            const int c0  = (lane & 7) * 8;
            uint4 o;
            o.x = pkrtz(fb[row * 64 + ((c0 + 0) ^ sr)], fb[row * 64 + ((c0 + 1) ^ sr)]);
            o.y = pkrtz(fb[row * 64 + ((c0 + 2) ^ sr)], fb[row * 64 + ((c0 + 3) ^ sr)]);
            o.z = pkrtz(fb[row * 64 + ((c0 + 4) ^ sr)], fb[row * 64 + ((c0 + 5) ^ sr)]);
            o.w = pkrtz(fb[row * 64 + ((c0 + 6) ^ sr)], fb[row * 64 + ((c0 + 7) ^ sr)]);
            *(uint4*)((char*)Pt + (size_t)tile * 2048 + q * 1024 + lane * 16) = o;
        }

        #pragma unroll
        for (int t = 0; t < 4; ++t)
            #pragma unroll
            for (int r = 0; r < 4; ++r)
                fb[e * 64 + ((16 * t + 4 * g + r) ^ se)] = aB[t][r];
        #pragma unroll
        for (int q = 0; q < 2; ++q) {
            const int row = q * 8 + (lane >> 3);
            const int sr  = ((row & 1) << 4) | ((row >> 1) & 3);
            const int c0  = (lane & 7) * 8;
            uint4 o;
            o.x = pkrtz(fb[row * 64 + ((c0 + 0) ^ sr)], fb[row * 64 + ((c0 + 1) ^ sr)]);
            o.y = pkrtz(fb[row * 64 + ((c0 + 2) ^ sr)], fb[row * 64 + ((c0 + 3) ^ sr)]);
            o.z = pkrtz(fb[row * 64 + ((c0 + 4) ^ sr)], fb[row * 64 + ((c0 + 5) ^ sr)]);
            o.w = pkrtz(fb[row * 64 + ((c0 + 6) ^ sr)], fb[row * 64 + ((c0 + 7) ^ sr)]);
            *(uint4*)((char*)Pb + (size_t)tile * 2048 + q * 1024 + lane * 16) = o;
        }
    }
}

// ============ Hierarchical exclusive scan of cnt3[NCNT] -> off3 ============
extern "C" __global__ void __launch_bounds__(1024)
scanA_kernel(const int* __restrict__ cnt3, int* __restrict__ off3, int* __restrict__ bsum)
{
    __shared__ int sh[1024];
    const int t = threadIdx.x;
    const int i = blockIdx.x * 1024 + t;
    const int v = (i < NCNT) ? cnt3[i] : 0;
    sh[t] = v;
    __syncthreads();
    for (int off = 1; off < 1024; off <<= 1) {
        const int u = (t >= off) ? sh[t - off] : 0;
        __syncthreads();
        sh[t] += u;
        __syncthreads();
    }
    if (i < NCNT) off3[i] = sh[t] - v;
    if (t == 1023) bsum[blockIdx.x] = sh[1023];
}

extern "C" __global__ void __launch_bounds__(128)
scanB_kernel(int* __restrict__ bsum)
{
    __shared__ int sh[128];
    const int t = threadIdx.x;
    const int v = (t < SCANB2) ? bsum[t] : 0;
    sh[t] = v;
    __syncthreads();
    for (int off = 1; off < 128; off <<= 1) {
        const int u = (t >= off) ? sh[t - off] : 0;
        __syncthreads();
        sh[t] += u;
        __syncthreads();
    }
    if (t < SCANB2) bsum[t] = sh[t] - v;
}

extern "C" __global__ void __launch_bounds__(1024)
scanC_kernel(int* __restrict__ off3, const int* __restrict__ bsum)
{
    const int i = blockIdx.x * 1024 + threadIdx.x;
    if (i < NCNT) off3[i] += bsum[blockIdx.x];
}

// ============ Privatized scatter: LDS cursors, zero global atomics ============
extern "C" __global__ void __launch_bounds__(1024)
scatter3_kernel(const int* __restrict__ ei, const int* __restrict__ off3,
                unsigned* __restrict__ sedge)
{
    __shared__ int cur[NB];
    const int b   = blockIdx.x;                  // grid must be NBLK
    const int tid = threadIdx.x;
    for (int k = tid; k < NB; k += 1024) cur[k] = off3[k * NBLK + b];
    __syncthreads();
    const int i0 = b * EPB;
    for (int i = i0 + tid; i < i0 + EPB; i += 1024) {
        const int s = ei[i];
        const int d = ei[NE + i];
        const int pos = atomicAdd(&cur[d >> GSH], 1);   // LDS atomic
        sedge[pos] = (unsigned)s | ((unsigned)(d & (GSZ - 1)) << 17);
    }
}

// ============ Per-bucket exact refinement sort ============
extern "C" __global__ void __launch_bounds__(256)
sort2_kernel(const unsigned* __restrict__ sedge, const int* __restrict__ off3,
             int2* __restrict__ spair)
{
    __shared__ int hist[GSZ], base[GSZ], curs[GSZ];
    const int tid = threadIdx.x;
    const int b   = blockIdx.x;
    const int r0  = off3[b * NBLK];
    const int r1  = (b == NB - 1) ? NE : off3[(b + 1) * NBLK];

    if (tid < GSZ) hist[tid] = 0;
    __syncthreads();
    for (int i = r0 + tid; i < r1; i += 256)
        atomicAdd(&hist[(sedge[i] >> 17) & (GSZ - 1)], 1);
    __syncthreads();
    if (tid == 0) {
        int run = 0;
        for (int j = 0; j < GSZ; ++j) { base[j] = run; run += hist[j]; }
    }
    __syncthreads();
    if (tid < GSZ) curs[tid] = base[tid];
    __syncthreads();
    for (int i = r0 + tid; i < r1; i += 256) {
        const unsigned pk = sedge[i];
        const int dl = (pk >> 17) & (GSZ - 1);
        const int pos = r0 + atomicAdd(&curs[dl], 1);
        spair[pos] = make_int2((int)(pk & 0x1FFFFu), (b << GSH) | dl);
    }
}

// ============ Edge kernel (sorted): R12-exact register-run accumulation ====
// LDS transpose buffer stride = 72 words: conflict-free b128 writes, 2-way reads.
extern "C" __global__ void __launch_bounds__(256, 2)
edge_kernel_sorted(const unsigned short* __restrict__ Pt, const unsigned short* __restrict__ Pb,
                   const float* __restrict__ x, const int2* __restrict__ spair,
                   const float* __restrict__ We2, const float* __restrict__ be2,
                   const float* __restrict__ Winf, const float* __restrict__ binf,
                   float* __restrict__ mi)
{
    __shared__ float fx[4][16 * FSTR];   // 18 KB
    const int tid  = threadIdx.x;
    const int wib  = tid >> 6;
    const int lane = tid & 63;
    const int e = lane & 15, g = lane >> 4;
    float* fb = &fx[wib][0];

    bf16x8 A2[4][2];                        // fp16 fragments
    f32x4 b2r[4], wir[4];
    #pragma unroll
    for (int t = 0; t < 4; ++t) {
        #pragma unroll
        for (int ks = 0; ks < 2; ++ks) {
            bf16x8 a;
            #pragma unroll
            for (int j = 0; j < 8; ++j)
                a[j] = f2h(We2[(32 * ks + 8 * g + j) * 64 + 16 * t + e]);
            A2[t][ks] = a;
        }
        #pragma unroll
        for (int r = 0; r < 4; ++r) {
            b2r[t][r] = be2[16 * t + 4 * g + r];
            wir[t][r] = Winf[16 * t + 4 * g + r];
        }
    }
    const float binf0 = binf[0];

    const int NT     = NE / 16;
    const int nwaves = gridDim.x * 4;
    const int gwid   = blockIdx.x * 4 + wib;
    const int chunk  = (NT + nwaves - 1) / nwaves;
    const int t0 = gwid * chunk;
    const int t1 = (t0 + chunk < NT) ? t0 + chunk : NT;

    float racc  = 0.f;   // running row accumulator, channel = lane
    int   rrow  = -1;    // wave-uniform current node id

    for (int tile = t0; tile < t1; ++tile) {
        const int eid = tile * 16 + e;
        const int2 sd = spair[eid];
        const int sN = sd.x;
        const int dN = sd.y;

        const float dx = x[dN * 3 + 0] - x[sN * 3 + 0];
        const float dy = x[dN * 3 + 1] - x[sN * 3 + 1];
        const float dz = x[dN * 3 + 2] - x[sN * 3 + 2];
        const float dsq = dx * dx + dy * dy + dz * dz;
        const float edis = sigmoidf_(TEMP / (sqrtf(dsq) + 1e-8f));

        // B2 frags: relu(Pt[dst] + Pb[src]) in packed fp16
        bf16x8 B2[2];
        #pragma unroll
        for (int ks = 0; ks < 2; ++ks) {
            const uint4 ut = *(const uint4*)(Pt + (size_t)dN * 64 + 32 * ks + 8 * g);
            const uint4 ub = *(const uint4*)(Pb + (size_t)sN * 64 + 32 * ks + 8 * g);
            union { uint4 u; bf16x8 b; } cvt;
            cvt.u.x = pk_add_relu(ut.x, ub.x);
            cvt.u.y = pk_add_relu(ut.y, ub.y);
            cvt.u.z = pk_add_relu(ut.z, ub.z);
            cvt.u.w = pk_add_relu(ut.w, ub.w);
            B2[ks] = cvt.b;
        }

        f32x4 acc2[4];
        #pragma unroll
        for (int t = 0; t < 4; ++t) {
            acc2[t] = b2r[t];
            #pragma unroll
            for (int ks = 0; ks < 2; ++ks)
                acc2[t] = __builtin_amdgcn_mfma_f32_16x16x32_f16(A2[t][ks], B2[ks], acc2[t], 0, 0, 0);
        }

        float m[4][4];
        float p = 0.f;
        #pragma unroll
        for (int t = 0; t < 4; ++t)
            #pragma unroll
            for (int r = 0; r < 4; ++r) {
                m[t][r] = fmaxf(acc2[t][r], 0.f);
                p = fmaf(m[t][r], wir[t][r], p);
            }
        p += __shfl_xor(p, 16);
        p += __shfl_xor(p, 32);
        const float w = sigmoidf_((p + binf0) * edis);

        // transpose via 4x ds_write_b128, natural channel order, stride-72 rows
        #pragma unroll
        for (int t = 0; t < 4; ++t) {
            float4 v;
            v.x = m[t][0] * w; v.y = m[t][1] * w;
            v.z = m[t][2] * w; v.w = m[t][3] * w;
            *(float4*)&fb[e * FSTR + 16 * t + 4 * g] = v;
        }

        #pragma unroll
        for (int i = 0; i < 16; ++i) {
            const int row = __builtin_amdgcn_readlane(dN, i);
            const float v = fb[i * FSTR + lane];
            if (row != rrow) {
                if (rrow >= 0) atomicAdd(mi + (size_t)rrow * 64 + lane, racc);
                rrow = row; racc = v;
            } else {
                racc += v;
            }
        }
    }
    if (rrow >= 0) atomicAdd(mi + (size_t)rrow * 64 + lane, racc);
}

// ============ Edge kernel (unsorted fallback, small-ws path) ============
extern "C" __global__ void __launch_bounds__(256, 2)
edge_kernel_unsorted(const unsigned short* __restrict__ Pt, const unsigned short* __restrict__ Pb,
                     const float* __restrict__ x, const int* __restrict__ ei,
                     const float* __restrict__ We2, const float* __restrict__ be2,
                     const float* __restrict__ Winf, const float* __restrict__ binf,
                     float* __restrict__ mi)
{
    __shared__ float fx[4][16 * FSTR];
    const int tid  = threadIdx.x;
    const int wib  = tid >> 6;
    const int lane = tid & 63;
    const int e = lane & 15, g = lane >> 4;
    float* fb = &fx[wib][0];

    bf16x8 A2[4][2];
    f32x4 b2r[4], wir[4];
    #pragma unroll
    for (int t = 0; t < 4; ++t) {
        #pragma unroll
        for (int ks = 0; ks < 2; ++ks) {
            bf16x8 a;
            #pragma unroll
            for (int j = 0; j < 8; ++j)
                a[j] = f2h(We2[(32 * ks + 8 * g + j) * 64 + 16 * t + e]);
            A2[t][ks] = a;
        }
        #pragma unroll
        for (int r = 0; r < 4; ++r) {
            b2r[t][r] = be2[16 * t + 4 * g + r];
            wir[t][r] = Winf[16 * t + 4 * g + r];
        }
    }
    const float binf0 = binf[0];

    const int gwid = blockIdx.x * 4 + wib;
    const int nw   = gridDim.x * 4;

    for (int tile = gwid; tile < NE / 16; tile += nw) {
        const int eid = tile * 16 + e;
        const int sN = ei[eid];
        const int dN = ei[NE + eid];

        const float dx = x[dN * 3 + 0] - x[sN * 3 + 0];
        const float dy = x[dN * 3 + 1] - x[sN * 3 + 1];
        const float dz = x[dN * 3 + 2] - x[sN * 3 + 2];
        const float dsq = dx * dx + dy * dy + dz * dz;
        const float edis = sigmoidf_(TEMP / (sqrtf(dsq) + 1e-8f));

        bf16x8 B2[2];
        #pragma unroll
        for (int ks = 0; ks < 2; ++ks) {
            const uint4 ut = *(const uint4*)(Pt + (size_t)dN * 64 + 32 * ks + 8 * g);
            const uint4 ub = *(const uint4*)(Pb + (size_t)sN * 64 + 32 * ks + 8 * g);
            union { uint4 u; bf16x8 b; } cvt;
            cvt.u.x = pk_add_relu(ut.x, ub.x);
            cvt.u.y = pk_add_relu(ut.y, ub.y);
            cvt.u.z = pk_add_relu(ut.z, ub.z);
            cvt.u.w = pk_add_relu(ut.w, ub.w);
            B2[ks] = cvt.b;
        }

        f32x4 acc2[4];
        #pragma unroll
        for (int t = 0; t < 4; ++t) {
            acc2[t] = b2r[t];
            #pragma unroll
            for (int ks = 0; ks < 2; ++ks)
                acc2[t] = __builtin_amdgcn_mfma_f32_16x16x32_f16(A2[t][ks], B2[ks], acc2[t], 0, 0, 0);
        }

        float m[4][4];
        float p = 0.f;
        #pragma unroll
        for (int t = 0; t < 4; ++t)
            #pragma unroll
            for (int r = 0; r < 4; ++r) {
                m[t][r] = fmaxf(acc2[t][r], 0.f);
                p = fmaf(m[t][r], wir[t][r], p);
            }
        p += __shfl_xor(p, 16);
        p += __shfl_xor(p, 32);
        const float w = sigmoidf_((p + binf0) * edis);

        #pragma unroll
        for (int t = 0; t < 4; ++t) {
            float4 v;
            v.x = m[t][0] * w; v.y = m[t][1] * w;
            v.z = m[t][2] * w; v.w = m[t][3] * w;
            *(float4*)&fb[e * FSTR + 16 * t + 4 * g] = v;
        }

        #pragma unroll
        for (int i = 0; i < 16; ++i) {
            const int row = __shfl(dN, i);
            const float v = fb[i * FSTR + lane];
            atomicAdd(mi + (size_t)row * 64 + lane, v);
        }
    }
}

// ============ Node kernel: all-f16 B2B MFMA + residual + LayerNorm =============
extern "C" __global__ void __launch_bounds__(256, 2)
node_kernel(const float* __restrict__ h, const float* __restrict__ mi_,
            const float* __restrict__ Wn1, const float* __restrict__ bn1,
            const float* __restrict__ Wn2, const float* __restrict__ bn2,
            const float* __restrict__ lng, const float* __restrict__ lnb,
            float* __restrict__ out)
{
    __shared__ unsigned xlds[4][16 * 32];
    const int tid  = threadIdx.x;
    const int wib  = tid >> 6;
    const int lane = tid & 63;
    const int e = lane & 15, g = lane >> 4;
    unsigned* tb = &xlds[wib][0];
    const int sw = (e & 7) << 2;

    bf16x8 A1[4][4], A2[4][2];   // f16 payload
    f32x4 b1r[4], b2r[4], gr[4], br[4];
    #pragma unroll
    for (int t = 0; t < 4; ++t) {
        #pragma unroll
        for (int ks = 0; ks < 4; ++ks) {
            bf16x8 a;
            #pragma unroll
            for (int j = 0; j < 8; ++j)
                a[j] = f2h(Wn1[(32 * ks + 8 * g + j) * 64 + 16 * t + e]);
            A1[t][ks] = a;
        }
        #pragma unroll
        for (int ks = 0; ks < 2; ++ks) {
            bf16x8 a;
            #pragma unroll
            for (int j = 0; j < 8; ++j)
                a[j] = f2h(Wn2[(32 * ks + 8 * g + j) * 64 + 16 * t + e]);
            A2[t][ks] = a;
        }
        #pragma unroll
        for (int r = 0; r < 4; ++r) {
            b1r[t][r] = bn1[16 * t + 4 * g + r];
            b2r[t][r] = bn2[16 * t + 4 * g + r];
            gr[t][r]  = lng[16 * t + 4 * g + r];
            br[t][r]  = lnb[16 * t + 4 * g + r];
        }
    }

    const int gwid = blockIdx.x * 4 + wib;
    const int nw   = gridDim.x * 4;

    for (int tile = gwid; tile < NN / 16; tile += nw) {
        const int node = tile * 16 + e;

        bf16x8 B1[4];
        #pragma unroll
        for (int ks = 0; ks < 4; ++ks) {
            const float* srcp = (ks < 2) ? mi_ : h;
            const float4* p = (const float4*)(srcp + (size_t)node * 64 + (ks & 1) * 32 + 8 * g);
            const float4 f0 = p[0], f1 = p[1];
            union { uint4 u; bf16x8 b; } cvt;
            cvt.u.x = pkrtz(f0.x, f0.y); cvt.u.y = pkrtz(f0.z, f0.w);
            cvt.u.z = pkrtz(f1.x, f1.y); cvt.u.w = pkrtz(f1.z, f1.w);
            B1[ks] = cvt.b;
        }

        f32x4 acc1[4];
        #pragma unroll
        for (int t = 0; t < 4; ++t) {
            acc1[t] = b1r[t];
            #pragma unroll
            for (int ks = 0; ks < 4; ++ks)
                acc1[t] = __builtin_amdgcn_mfma_f32_16x16x32_f16(A1[t][ks], B1[ks], acc1[t], 0, 0, 0);
        }

        #pragma unroll
        for (int t = 0; t < 4; ++t) {
            const float r0 = fmaxf(acc1[t][0], 0.f), r1 = fmaxf(acc1[t][1], 0.f);
            const float r2 = fmaxf(acc1[t][2], 0.f), r3 = fmaxf(acc1[t][3], 0.f);
            tb[e * 32 + ((8 * t + 2 * g + 0) ^ sw)] = pkrtz(r0, r1);
            tb[e * 32 + ((8 * t + 2 * g + 1) ^ sw)] = pkrtz(r2, r3);
        }
        bf16x8 B2[2];
        #pragma unroll
        for (int ks = 0; ks < 2; ++ks) {
            union { uint4 u; bf16x8 b; } cvt;
            cvt.u = *(const uint4*)&tb[e * 32 + ((16 * ks + 4 * g) ^ sw)];
            B2[ks] = cvt.b;
        }

        f32x4 acc2[4];
        #pragma unroll
        for (int t = 0; t < 4; ++t) {
            acc2[t] = b2r[t];
            #pragma unroll
            for (int ks = 0; ks < 2; ++ks)
                acc2[t] = __builtin_amdgcn_mfma_f32_16x16x32_f16(A2[t][ks], B2[ks], acc2[t], 0, 0, 0);
        }

        float z[4][4];
        float s1 = 0.f, s2 = 0.f;
        #pragma unroll
        for (int t = 0; t < 4; ++t) {
            const float4 hres = *(const float4*)(h + (size_t)node * 64 + 16 * t + 4 * g);
            #pragma unroll
            for (int r = 0; r < 4; ++r) {
                z[t][r] = acc2[t][r] + hres[r];
                s1 += z[t][r];
                s2 = fmaf(z[t][r], z[t][r], s2);
            }
        }
        s1 += __shfl_xor(s1, 16); s1 += __shfl_xor(s1, 32);
        s2 += __shfl_xor(s2, 16); s2 += __shfl_xor(s2, 32);
        const float mu   = s1 * (1.0f / 64.0f);
        const float var  = s2 * (1.0f / 64.0f) - mu * mu;
        const float rstd = rsqrtf(var + LNEPS);

        #pragma unroll
        for (int t = 0; t < 4; ++t) {
            float4 o;
            #pragma unroll
            for (int r = 0; r < 4; ++r)
                o[r] = (z[t][r] - mu) * rstd * gr[t][r] + br[t][r];
            *(float4*)(out + (size_t)node * 64 + 16 * t + 4 * g) = o;
        }
    }
}

extern "C" void kernel_launch(void* const* d_in, const int* in_sizes, int n_in,
                              void* d_out, int out_size, void* d_ws, size_t ws_size,
                              hipStream_t stream)
{
    const float* h    = (const float*)d_in[0];
    const float* x    = (const float*)d_in[1];
    const int*   ei   = (const int*)d_in[2];
    const float* We1  = (const float*)d_in[3];
    const float* be1  = (const float*)d_in[4];
    const float* We2  = (const float*)d_in[5];
    const float* be2  = (const float*)d_in[6];
    const float* Winf = (const float*)d_in[7];
    const float* binf = (const float*)d_in[8];
    const float* Wn1  = (const float*)d_in[9];
    const float* bn1  = (const float*)d_in[10];
    const float* Wn2  = (const float*)d_in[11];
    const float* bn2  = (const float*)d_in[12];
    const float* lng  = (const float*)d_in[13];
    const float* lnb  = (const float*)d_in[14];
    float* out = (float*)d_out;

    const size_t mi_bytes = (size_t)NN * HDIM * sizeof(float);          // 25.6 MB
    const size_t p_bytes  = (size_t)NN * HDIM * sizeof(unsigned short); // 12.8 MB
    const size_t sp_bytes = (size_t)NE * sizeof(int2);                  // 12.8 MB
    const size_t se_bytes = (size_t)NE * sizeof(unsigned);              //  6.4 MB
    const size_t c3_bytes = (size_t)NCNT * sizeof(int);                 //  0.4 MB
    const size_t scratch  = se_bytes + 2 * c3_bytes + SCANB2 * sizeof(int);

    const size_t need_sorted = mi_bytes + 2 * p_bytes + sp_bytes;

    if (ws_size >= need_sorted && mi_bytes >= scratch) {
        char* ws = (char*)d_ws;
        float*          mi    = (float*)ws;              ws += mi_bytes;
        unsigned short* Pt    = (unsigned short*)ws;     ws += p_bytes;
        unsigned short* Pb    = (unsigned short*)ws;     ws += p_bytes;
        int2*           spair = (int2*)ws;

        char* mis = (char*)mi;
        unsigned* sedge = (unsigned*)mis;                          // [0, 6.4 MB)
        int*      cnt3  = (int*)(mis + se_bytes);                  // 0.4 MB
        int*      off3  = (int*)(mis + se_bytes + c3_bytes);       // 0.4 MB
        int*      bsum  = (int*)(mis + se_bytes + 2 * c3_bytes);   // 392 B

        (void)hipMemcpyAsync(out + (size_t)NN * HDIM, x, (size_t)NN * 3 * sizeof(float),
                             hipMemcpyDeviceToDevice, stream);

        front_kernel<<<NBLK + 512, 256, 0, stream>>>(h, We1, be1, Pt, Pb, ei, cnt3);
        scanA_kernel<<<SCANB2, 1024, 0, stream>>>(cnt3, off3, bsum);
        scanB_kernel<<<1, 128, 0, stream>>>(bsum);
        scanC_kernel<<<SCANB2, 1024, 0, stream>>>(off3, bsum);
        scatter3_kernel<<<NBLK, 1024, 0, stream>>>(ei, off3, sedge);
        sort2_kernel<<<NB, 256, 0, stream>>>(sedge, off3, spair);
        (void)hipMemsetAsync(mi, 0, mi_bytes, stream);   // after sort2: frees aliases
        edge_kernel_sorted<<<2048, 256, 0, stream>>>(Pt, Pb, x, spair, We2, be2, Winf, binf, mi);
        node_kernel<<<512, 256, 0, stream>>>(h, mi, Wn1, bn1, Wn2, bn2, lng, lnb, out);
    } else {
        float* mi;
        unsigned short* Pt;
        unsigned short* Pb;
        if (ws_size >= mi_bytes + 2 * p_bytes) {
            mi = (float*)d_ws;
            Pt = (unsigned short*)((char*)d_ws + mi_bytes);
            Pb = (unsigned short*)((char*)d_ws + mi_bytes + p_bytes);
        } else {
            mi = out;
            Pt = (unsigned short*)d_ws;
            Pb = (unsigned short*)((char*)d_ws + p_bytes);
        }

        (void)hipMemsetAsync(mi, 0, mi_bytes, stream);
        (void)hipMemcpyAsync(out + (size_t)NN * HDIM, x, (size_t)NN * 3 * sizeof(float),
                             hipMemcpyDeviceToDevice, stream);

        front_kernel<<<NBLK + 512, 256, 0, stream>>>(h, We1, be1, Pt, Pb, ei,
                                                     (int*)((char*)d_ws));
        edge_kernel_unsorted<<<2048, 256, 0, stream>>>(Pt, Pb, x, ei, We2, be2, Winf, binf, mi);
        node_kernel<<<512, 256, 0, stream>>>(h, mi, Wn1, bn1, Wn2, bn2, lng, lnb, out);
    }
}